// Round 4
// baseline (1153.765 us; speedup 1.0000x reference)
//
#include <hip/hip_runtime.h>

typedef _Float16 f16;
typedef _Float16 f16x8 __attribute__((ext_vector_type(8)));
typedef float f32x4 __attribute__((ext_vector_type(4)));

#define MFMA16(a, b, c) __builtin_amdgcn_mfma_f32_16x16x32_f16((a), (b), (c), 0, 0, 0)

__device__ __forceinline__ float sigm(float v) { return 1.0f / (1.0f + __expf(-v)); }
__device__ __forceinline__ float tanh_(float v) { return 1.0f - 2.0f / (__expf(2.0f * v) + 1.0f); }

// ======================= Kernel A: ConvLSTM recurrence =======================
// 256 threads = 4 waves = mg(0..3); 4 samples/block; n = sample*16 + pos (64).
// m = ch*4 + gate: wave mg owns m in [mg*32, mg*32+32) (two 16-row tiles mti).
// D rows = lk*4+r -> gate=r, ch = mg*8 + mti*4 + lk -> cell update in-register.
// Conv = 9 tap-GEMMs (K=32 h) + 1 im2col x-GEMM (K: 27 x + k27=bias, 28..31=0).
// Taps 0..4 A-frags in registers; taps 5..8 streamed from LDS.
// All hot-loop LDS strides are 72 B (18 dwords) -> near-conflict-free b128.
//
// LDS map (bytes):
//   hpad [4 b][36 cell][36 sl f16]   0     .. 10368   (cell 72 B, sample 2592 B)
//   xs   [4 b][16 pos][36 sl f16]    10368 .. 14976   (pos 72 B, sample 1152 B)
//   cmp  [2 buf][4 b][64 sl f16]     14976 .. 16000   (buf 512 B; slots 48..63 = 0)
//   WS   [4 tp][128 m][36 sl f16]    16000 .. 52864   (m row 72 B; also stage scratch)
//   dump 64 B                        52864 .. 52928
#define HP 0
#define XS 10368
#define CMP 14976
#define WS 16000
#define DUMP 52864
#define SMEMA 52928

extern "C" __global__ __launch_bounds__(256, 3)
void hwq_rec(const float* __restrict__ gx, const float* __restrict__ ghour,
             const float* __restrict__ gcw, const float* __restrict__ gcb,
             const float* __restrict__ ghw1, const float* __restrict__ ghb1,
             const float* __restrict__ ghw2, const float* __restrict__ ghb2,
             f16* __restrict__ wz)
{
  __shared__ __align__(16) char smem[SMEMA];
  const int tid = threadIdx.x;
  const int lane = tid & 63;
  const int mg = tid >> 6;
  const int lr = lane & 15;
  const int lk = lane >> 4;
  const int bg = blockIdx.x << 2;                   // 4 samples/block
  const float* gxb = gx + (size_t)bg * 576;

  // ---- 1. zero hpad + xs + cmp ----
  {
    float* za = (float*)smem;                        // hpad+xs+cmp contiguous: 16000 B
    for (int i = tid; i < 4000; i += 256) za[i] = 0.0f;
    __syncthreads();
  }

  // ---- 2. x-part weights (+bias as k=27) staged into WS, gathered to regs ----
  f16x8 Ax[2];
  {
    f16* axs = (f16*)(smem + WS);   // [128 m][32 k] contiguous (64 B rows)
    for (int i = tid; i < 4096; i += 256) {
      int m = i >> 5, k = i & 31;
      int oc = ((m & 3) << 5) + (m >> 2);
      f16 v = (f16)0.0f;
      if (k < 27) {
        int tap = k / 3, ic = k - 3 * tap;
        v = (f16)gcw[oc * 315 + ic * 9 + tap];
      } else if (k == 27) {
        v = (f16)gcb[oc];
      }
      axs[i] = v;
    }
    __syncthreads();
    #pragma unroll
    for (int mti = 0; mti < 2; ++mti)
      Ax[mti] = *(const f16x8*)(smem + WS + (mg * 32 + mti * 16 + lr) * 64 + lk * 16);
    __syncthreads();
  }

  // ---- 3. reg-tap A-frags (taps 0..4), 4 chunks of 32 m-rows via WS scratch ----
  f16x8 Ah[5][2];
  {
    f16* wst = (f16*)(smem + WS);   // [32 mrow][288 = ch*9+tap]
    #pragma unroll
    for (int c = 0; c < 4; ++c) {
      for (int i = tid; i < 9216; i += 256) {
        int mrow = i / 288, rem = i - mrow * 288;
        int m = c * 32 + mrow;
        int oc = ((m & 3) << 5) + (m >> 2);
        wst[i] = (f16)gcw[oc * 315 + 27 + rem];
      }
      __syncthreads();
      if (mg == c) {
        #pragma unroll
        for (int mti = 0; mti < 2; ++mti)
          #pragma unroll
          for (int tap = 0; tap < 5; ++tap) {
            f16x8 f;
            #pragma unroll
            for (int j = 0; j < 8; ++j)
              f[j] = wst[(mti * 16 + lr) * 288 + (lk * 8 + j) * 9 + tap];
            Ah[tap][mti] = f;
          }
      }
      __syncthreads();
    }
  }

  // ---- 4. streamed-tap weights (taps 5..8) into persistent WS [tp][m][36sl] ----
  {
    f16* wl = (f16*)(smem + WS);
    for (int i = tid; i < 16384; i += 256) {
      int tp = i >> 12, rem = i & 4095;
      int m = rem >> 5, k = rem & 31;
      int oc = ((m & 3) << 5) + (m >> 2);
      wl[tp * 4608 + m * 36 + k] = (f16)gcw[oc * 315 + 27 + k * 9 + 5 + tp];
    }
  }

  // ---- 5. im2col slot table (t-invariant): (src_cmp_rel<<16 | dst_byte) ----
  unsigned pk[7];
  #pragma unroll
  for (int s = 0; s < 7; ++s) {
    int e = tid + s * 256;
    unsigned src = 96;                               // cmp slot 48 (always 0)
    unsigned dst = DUMP + ((tid & 31) << 1);
    if (e < 1728) {
      int b = e / 432, r1 = e - b * 432;
      int pos = r1 / 27, k = r1 - pos * 27;
      int tap = k / 3, ic = k - 3 * tap;
      int py = (pos >> 2) + tap / 3 - 1, px = (pos & 3) + tap % 3 - 1;
      if (py >= 0 && py < 4 && px >= 0 && px < 4)
        src = b * 128 + (ic * 16 + py * 4 + px) * 2;
      dst = XS + b * 1152 + pos * 72 + k * 2;
    }
    pk[s] = (src << 16) | dst;
  }

  // ---- 6. bias channel, stage cmp(0)/cmp(1), expand xs(0) ----
  if (tid < 64) {
    int b = tid >> 4, pos = tid & 15;
    *(f16*)(smem + XS + b * 1152 + pos * 72 + 54) = (f16)1.0f;   // k=27 -> 1.0
  }
  if (tid < 192) {
    int b = tid / 48, rem = tid - b * 48;
    *(f16*)(smem + CMP + b * 128 + rem * 2)       = (f16)gxb[(size_t)b * 576 + rem];
    *(f16*)(smem + CMP + 512 + b * 128 + rem * 2) = (f16)gxb[(size_t)b * 576 + 48 + rem];
  }
  __syncthreads();
  #pragma unroll
  for (int s = 0; s < 7; ++s) {
    unsigned u = pk[s];
    *(f16*)(smem + (u & 0xffffu)) = *(const f16*)(smem + CMP + (u >> 16));
  }
  __syncthreads();

  // ---- hot-loop bases ----
  const int pp0 = (lr >> 2) * 6 + (lr & 3);
  const int hb = pp0 * 72 + lk * 16;                         // h B-frag base
  const int xb = XS + lr * 72 + lk * 16;                     // x B-frag base
  const int wb = (pp0 + 7) * 72 + (mg * 8 + lk) * 2;         // h' write base
  const int wa = WS + (mg * 32 + lr) * 72 + lk * 16;         // streamed A base

  float cst[2][4];
  #pragma unroll
  for (int mti = 0; mti < 2; ++mti)
    #pragma unroll
    for (int nt = 0; nt < 4; ++nt) cst[mti][nt] = 0.0f;

  for (int t = 0; t < 12; ++t) {
    // ======== phase B: GEMMs ========
    f32x4 acc[2][4];
    #pragma unroll
    for (int mti = 0; mti < 2; ++mti)
      #pragma unroll
      for (int nt = 0; nt < 4; ++nt) { f32x4 z = {0.f,0.f,0.f,0.f}; acc[mti][nt] = z; }

    // streamed taps 5..8 (A from LDS)
    #pragma unroll
    for (int tp = 0; tp < 4; ++tp) {
      const int tap = 5 + tp;
      const int to = ((tap / 3) * 6 + (tap % 3)) * 72;
      f16x8 af0 = *(const f16x8*)(smem + wa + tp * 4608 * 2);
      f16x8 af1 = *(const f16x8*)(smem + wa + tp * 4608 * 2 + 16 * 72);
      #pragma unroll
      for (int nt = 0; nt < 4; ++nt) {
        f16x8 bf = *(const f16x8*)(smem + hb + nt * 2592 + to);
        acc[0][nt] = MFMA16(af0, bf, acc[0][nt]);
        acc[1][nt] = MFMA16(af1, bf, acc[1][nt]);
      }
    }
    // register taps 0..4
    #pragma unroll
    for (int tap = 0; tap < 5; ++tap) {
      const int to = ((tap / 3) * 6 + (tap % 3)) * 72;
      #pragma unroll
      for (int nt = 0; nt < 4; ++nt) {
        f16x8 bf = *(const f16x8*)(smem + hb + nt * 2592 + to);
        acc[0][nt] = MFMA16(Ah[tap][0], bf, acc[0][nt]);
        acc[1][nt] = MFMA16(Ah[tap][1], bf, acc[1][nt]);
      }
    }
    // x + bias (im2col, clean b128)
    #pragma unroll
    for (int nt = 0; nt < 4; ++nt) {
      f16x8 bf = *(const f16x8*)(smem + xb + nt * 1152);
      acc[0][nt] = MFMA16(Ax[0], bf, acc[0][nt]);
      acc[1][nt] = MFMA16(Ax[1], bf, acc[1][nt]);
    }
    __syncthreads();

    // ======== phase C: cell update + staging ========
    #pragma unroll
    for (int mti = 0; mti < 2; ++mti) {
      #pragma unroll
      for (int nt = 0; nt < 4; ++nt) {
        float ig = sigm(acc[mti][nt][0]);
        float fg = sigm(acc[mti][nt][1]);
        float og = sigm(acc[mti][nt][2]);
        float gg = tanh_(acc[mti][nt][3]);
        float cn = fg * cst[mti][nt] + ig * gg;
        cst[mti][nt] = cn;
        f16 h = (f16)(og * tanh_(cn));
        if (t < 11) {
          *(f16*)(smem + wb + nt * 2592 + mti * 8) = h;
        } else {
          int ch = mg * 8 + mti * 4 + lk;
          wz[(size_t)(bg + nt) * 544 + ch * 16 + lr] = h;
        }
      }
    }
    if (t < 11) {
      // stage cmp(t+2), expand xs(t+1) from cmp((t+1)&1)
      if (t <= 9 && tid < 192) {
        int b = tid / 48, rem = tid - b * 48;
        *(f16*)(smem + CMP + (t & 1) * 512 + b * 128 + rem * 2) =
            (f16)gxb[(size_t)b * 576 + (t + 2) * 48 + rem];
      }
      const int cb = CMP + ((t + 1) & 1) * 512;
      #pragma unroll
      for (int s = 0; s < 7; ++s) {
        unsigned u = pk[s];
        *(f16*)(smem + (u & 0xffffu)) = *(const f16*)(smem + cb + (u >> 16));
      }
    } else if (tid < 128) {
      int b = tid >> 5, k2 = tid & 31;
      float h0 = ghour[bg + b];
      float a = ghb2[k2];
      #pragma unroll
      for (int ii = 0; ii < 16; ++ii) {
        float u = fmaxf(h0 * ghw1[ii] + ghb1[ii], 0.0f);
        a += u * ghw2[ii * 32 + k2];
      }
      wz[(size_t)(bg + b) * 544 + 512 + k2] = (f16)a;
    }
    __syncthreads();
  }
}

// ======================= prep: weight transpose fp32->f16 =======================
extern "C" __global__ void hwq_prep(const float* __restrict__ gdw1,
                                    const float* __restrict__ gdw2,
                                    const float* __restrict__ gdw3,
                                    f16* __restrict__ w1t, f16* __restrict__ w2t,
                                    f16* __restrict__ w3t)
{
  int i0 = blockIdx.x * 256 + threadIdx.x;
  int stride = gridDim.x * 256;
  for (int idx = i0; idx < 139264; idx += stride) {
    int n = idx / 544, k = idx - n * 544;
    w1t[idx] = (f16)gdw1[k * 256 + n];
  }
  for (int idx = i0; idx < 32768; idx += stride) {
    int n = idx >> 8, k = idx & 255;
    w2t[idx] = (f16)gdw2[k * 128 + n];
  }
  for (int idx = i0; idx < 4096; idx += stride) {
    int n = idx >> 7, k = idx & 127;
    w3t[idx] = (n < 30) ? (f16)gdw3[k * 30 + n] : (f16)0.0f;
  }
}

// ======================= Kernel B: decoder MLP =======================
extern "C" __global__ __launch_bounds__(256, 2)
void hwq_dec(const f16* __restrict__ wz, const f16* __restrict__ w1t,
             const f16* __restrict__ w2t, const f16* __restrict__ w3t,
             const float* __restrict__ gdb1, const float* __restrict__ gdb2,
             const float* __restrict__ gdb3, float* __restrict__ gout)
{
  __shared__ __align__(16) char smem[55296];
  f16* a1 = (f16*)smem;               // [64][280]
  f16* a2 = (f16*)(smem + 35840);     // [64][152]
  const int tid = threadIdx.x;
  const int lane = tid & 63;
  const int wv = tid >> 6;
  const int lr = lane & 15;
  const int lk = lane >> 4;
  const int s0 = blockIdx.x << 6;

  f32x4 acc1[4][4];
  #pragma unroll
  for (int nt = 0; nt < 4; ++nt) {
    float bb = gdb1[wv * 64 + nt * 16 + lr];
    f32x4 bv = {bb, bb, bb, bb};
    #pragma unroll
    for (int mt = 0; mt < 4; ++mt) acc1[mt][nt] = bv;
  }
  for (int kt = 0; kt < 17; ++kt) {
    f16x8 af[4];
    #pragma unroll
    for (int mt = 0; mt < 4; ++mt)
      af[mt] = *(const f16x8*)(wz + (size_t)(s0 + mt * 16 + lr) * 544 + kt * 32 + lk * 8);
    #pragma unroll
    for (int nt = 0; nt < 4; ++nt) {
      f16x8 bf = *(const f16x8*)(w1t + (size_t)(wv * 64 + nt * 16 + lr) * 544 + kt * 32 + lk * 8);
      #pragma unroll
      for (int mt = 0; mt < 4; ++mt)
        acc1[mt][nt] = MFMA16(af[mt], bf, acc1[mt][nt]);
    }
  }
  #pragma unroll
  for (int mt = 0; mt < 4; ++mt)
    #pragma unroll
    for (int nt = 0; nt < 4; ++nt) {
      int n = wv * 64 + nt * 16 + lr;
      #pragma unroll
      for (int r = 0; r < 4; ++r)
        a1[(mt * 16 + lk * 4 + r) * 280 + n] = (f16)fmaxf(acc1[mt][nt][r], 0.0f);
    }
  __syncthreads();

  f32x4 acc2[4][2];
  #pragma unroll
  for (int nt = 0; nt < 2; ++nt) {
    float bb = gdb2[wv * 32 + nt * 16 + lr];
    f32x4 bv = {bb, bb, bb, bb};
    #pragma unroll
    for (int mt = 0; mt < 4; ++mt) acc2[mt][nt] = bv;
  }
  for (int kt = 0; kt < 8; ++kt) {
    f16x8 af[4];
    #pragma unroll
    for (int mt = 0; mt < 4; ++mt)
      af[mt] = *(const f16x8*)(a1 + (mt * 16 + lr) * 280 + kt * 32 + lk * 8);
    #pragma unroll
    for (int nt = 0; nt < 2; ++nt) {
      f16x8 bf = *(const f16x8*)(w2t + (size_t)(wv * 32 + nt * 16 + lr) * 256 + kt * 32 + lk * 8);
      #pragma unroll
      for (int mt = 0; mt < 4; ++mt)
        acc2[mt][nt] = MFMA16(af[mt], bf, acc2[mt][nt]);
    }
  }
  __syncthreads();
  #pragma unroll
  for (int mt = 0; mt < 4; ++mt)
    #pragma unroll
    for (int nt = 0; nt < 2; ++nt) {
      int n = wv * 32 + nt * 16 + lr;
      #pragma unroll
      for (int r = 0; r < 4; ++r)
        a2[(mt * 16 + lk * 4 + r) * 152 + n] = (f16)fmaxf(acc2[mt][nt][r], 0.0f);
    }
  __syncthreads();

  if (wv < 2) {
    int n = wv * 16 + lr;
    float bb = (n < 30) ? gdb3[n] : 0.0f;
    f32x4 acc3[4];
    #pragma unroll
    for (int mt = 0; mt < 4; ++mt) { f32x4 bv = {bb, bb, bb, bb}; acc3[mt] = bv; }
    #pragma unroll
    for (int kt = 0; kt < 4; ++kt) {
      f16x8 bf = *(const f16x8*)(w3t + n * 128 + kt * 32 + lk * 8);
      #pragma unroll
      for (int mt = 0; mt < 4; ++mt) {
        f16x8 af = *(const f16x8*)(a2 + (mt * 16 + lr) * 152 + kt * 32 + lk * 8);
        acc3[mt] = MFMA16(af, bf, acc3[mt]);
      }
    }
    if (n < 30) {
      #pragma unroll
      for (int mt = 0; mt < 4; ++mt)
        #pragma unroll
        for (int r = 0; r < 4; ++r)
          gout[(size_t)(s0 + mt * 16 + lk * 4 + r) * 30 + n] = sigm(acc3[mt][r]);
    }
  }
}

// ======================= Fallback: monolithic kernel (R1) =======================
typedef _Float16 f16x4m __attribute__((ext_vector_type(4)));
#define OFF_B 46080
#define SMEM_BYTES (46080 + 17408)

extern "C" __global__ __launch_bounds__(256, 1)
void hwq_fused_mono(const float* __restrict__ gx, const float* __restrict__ ghour,
               const float* __restrict__ gcw, const float* __restrict__ gcb,
               const float* __restrict__ ghw1, const float* __restrict__ ghb1,
               const float* __restrict__ ghw2, const float* __restrict__ ghb2,
               const float* __restrict__ gdw1, const float* __restrict__ gdb1,
               const float* __restrict__ gdw2, const float* __restrict__ gdb2,
               const float* __restrict__ gdw3, const float* __restrict__ gdb3,
               float* __restrict__ gout)
{
  __shared__ __align__(16) char smem[SMEM_BYTES];
  const int tid = threadIdx.x;
  const int lane = tid & 63;
  const int wv = tid >> 6;
  const int mg = wv & 1;
  const int ng = wv >> 1;
  const int lr = lane & 15;
  const int lk = lane >> 4;
  const int bg = blockIdx.x << 4;

  f16x8 Ah[9][4];
  {
    f16* wst = (f16*)(smem);
    #pragma unroll
    for (int c = 0; c < 2; ++c) {
      __syncthreads();
      for (int i = tid; i < 18432; i += 256) {
        int oc = i / 288, rem = i - oc * 288;
        wst[i] = (f16)gcw[(c * 64 + oc) * 315 + 27 + rem];
      }
      __syncthreads();
      #pragma unroll
      for (int g = 0; g < 2; ++g) {
        int ocl = g * 32 + mg * 16 + lr;
        #pragma unroll
        for (int tap = 0; tap < 9; ++tap) {
          f16x8 f;
          #pragma unroll
          for (int j = 0; j < 8; ++j)
            f[j] = wst[ocl * 288 + (lk * 8 + j) * 9 + tap];
          Ah[tap][c * 2 + g] = f;
        }
      }
    }
  }
  f16x8 Ax[4];
  {
    f16* xw = (f16*)(smem + OFF_B);
    __syncthreads();
    for (int i = tid; i < 3456; i += 256) {
      int oc = i / 27, rem = i - oc * 27;
      xw[i] = (f16)gcw[oc * 315 + rem];
    }
    __syncthreads();
    #pragma unroll
    for (int mt = 0; mt < 4; ++mt) {
      int oc = mt * 32 + mg * 16 + lr;
      f16x8 f;
      #pragma unroll
      for (int j = 0; j < 8; ++j) {
        int k = lk * 8 + j;
        int tap = (k * 11) >> 5;
        int ic = k - 3 * tap;
        f16 v = (f16)0.0f;
        if (k < 27) v = xw[oc * 27 + ic * 9 + tap];
        f[j] = v;
      }
      Ax[mt] = f;
    }
    __syncthreads();
  }

  float bias[4][4];
  #pragma unroll
  for (int mt = 0; mt < 4; ++mt)
    #pragma unroll
    for (int r = 0; r < 4; ++r)
      bias[mt][r] = gcb[mt * 32 + mg * 16 + lk * 4 + r];

  {
    float* za = (float*)smem;
    for (int i = tid; i < 11520; i += 256) za[i] = 0.0f;
    float* zb = (float*)(smem + OFF_B);
    for (int i = tid; i < 1152; i += 256) zb[i] = 0.0f;
    __syncthreads();
    for (int i = tid; i < 768; i += 256) {
      int b = i / 48, rem = i - b * 48;
      int pos = rem & 15;
      int ic = rem >> 4;
      int pp = (pos >> 2) * 6 + (pos & 3) + 7;
      *(f16*)(smem + OFF_B + b * 288 + pp * 8 + ic * 2) =
          (f16)gx[(size_t)(bg + b) * 576 + rem];
    }
    __syncthreads();
  }

  int hbase[8], xbase[8], wbase[8];
  #pragma unroll
  for (int nt = 0; nt < 8; ++nt) {
    int n = ng * 128 + nt * 16 + lr;
    int b = n >> 4, pos = n & 15;
    int pp0 = (pos >> 2) * 6 + (pos & 3);
    hbase[nt] = b * 2880 + pp0 * 80 + lk * 16;
    xbase[nt] = OFF_B + b * 288 + pp0 * 8;
    wbase[nt] = b * 2880 + (pp0 + 7) * 80 + (mg * 16 + lk * 4) * 2;
  }
  int xoff[8], xval[8];
  #pragma unroll
  for (int j = 0; j < 8; ++j) {
    int k = lk * 8 + j;
    int tap = (k * 11) >> 5;
    int ic = k - 3 * tap;
    xoff[j] = ((tap / 3) * 6 + (tap % 3)) * 8 + ic * 2;
    xval[j] = (k < 27);
  }

  const int TOFF[9] = {0, 1, 2, 6, 7, 8, 12, 13, 14};

  f32x4 cst[8];
  #pragma unroll
  for (int nt = 0; nt < 8; ++nt) { f32x4 z = {0.f, 0.f, 0.f, 0.f}; cst[nt] = z; }

  for (int t = 0; t < 12; ++t) {
    f32x4 acc[4][8];
    #pragma unroll
    for (int mt = 0; mt < 4; ++mt) {
      f32x4 bi = {bias[mt][0], bias[mt][1], bias[mt][2], bias[mt][3]};
      #pragma unroll
      for (int nt = 0; nt < 8; ++nt) acc[mt][nt] = bi;
    }
    #pragma unroll
    for (int tap = 0; tap < 9; ++tap) {
      #pragma unroll
      for (int nt = 0; nt < 8; ++nt) {
        f16x8 bf = *(const f16x8*)(smem + hbase[nt] + TOFF[tap] * 80);
        #pragma unroll
        for (int mt = 0; mt < 4; ++mt)
          acc[mt][nt] = MFMA16(Ah[tap][mt], bf, acc[mt][nt]);
      }
    }
    #pragma unroll
    for (int nt = 0; nt < 8; ++nt) {
      f16x8 bf;
      #pragma unroll
      for (int j = 0; j < 8; ++j) {
        int a = xval[j] ? (xbase[nt] + xoff[j]) : OFF_B;
        bf[j] = *(const f16*)(smem + a);
      }
      #pragma unroll
      for (int mt = 0; mt < 4; ++mt)
        acc[mt][nt] = MFMA16(Ax[mt], bf, acc[mt][nt]);
    }
    __syncthreads();

    #pragma unroll
    for (int nt = 0; nt < 8; ++nt) {
      f16 hh[4];
      #pragma unroll
      for (int r = 0; r < 4; ++r) {
        float ig = sigm(acc[0][nt][r]);
        float fg = sigm(acc[1][nt][r]);
        float og = sigm(acc[2][nt][r]);
        float gg = tanh_(acc[3][nt][r]);
        float cn = fg * cst[nt][r] + ig * gg;
        cst[nt][r] = cn;
        hh[r] = (f16)(og * tanh_(cn));
      }
      if (t < 11) {
        f16x4m hv = {hh[0], hh[1], hh[2], hh[3]};
        *(f16x4m*)(smem + wbase[nt]) = hv;
      } else {
        int n = ng * 128 + nt * 16 + lr;
        int b = n >> 4, pos = n & 15;
        int ch0 = mg * 16 + lk * 4;
        #pragma unroll
        for (int r = 0; r < 4; ++r)
          *(f16*)(smem + OFF_B + b * 1088 + (ch0 + r) * 32 + pos * 2) = hh[r];
      }
    }
    if (t < 11) {
      for (int i = tid; i < 768; i += 256) {
        int b = i / 48, rem = i - b * 48;
        int pos = rem & 15;
        int ic = rem >> 4;
        int pp = (pos >> 2) * 6 + (pos & 3) + 7;
        *(f16*)(smem + OFF_B + b * 288 + pp * 8 + ic * 2) =
            (f16)gx[(size_t)(bg + b) * 576 + (t + 1) * 48 + rem];
      }
    } else {
      for (int i = tid; i < 512; i += 256) {
        int b = i >> 5, k2 = i & 31;
        float h0 = ghour[bg + b];
        float a = ghb2[k2];
        #pragma unroll
        for (int ii = 0; ii < 16; ++ii) {
          float u = fmaxf(h0 * ghw1[ii] + ghb1[ii], 0.0f);
          a += u * ghw2[ii * 32 + k2];
        }
        *(f16*)(smem + OFF_B + b * 1088 + (512 + k2) * 2) = (f16)a;
      }
    }
    __syncthreads();
  }

  f16* zz  = (f16*)(smem + OFF_B);
  f16* wch = (f16*)(smem);
  f16* a1  = (f16*)(smem + 16384);
  f16* a2  = (f16*)(smem + 24576);
  f16* w3s = (f16*)(smem + 28672);

  f32x4 acc1[4];
  #pragma unroll
  for (int i = 0; i < 4; ++i) { f32x4 z = {0.f, 0.f, 0.f, 0.f}; acc1[i] = z; }
  for (int kt = 0; kt < 17; ++kt) {
    __syncthreads();
    for (int i = tid; i < 8192; i += 256) {
      int k = i >> 8, n = i & 255;
      wch[i] = (f16)gdw1[(kt * 32 + k) * 256 + n];
    }
    __syncthreads();
    f16x8 af = *(const f16x8*)((char*)zz + lr * 1088 + (kt * 32 + lk * 8) * 2);
    #pragma unroll
    for (int nt = 0; nt < 4; ++nt) {
      int n = (wv * 4 + nt) * 16 + lr;
      f16x8 bf;
      #pragma unroll
      for (int j = 0; j < 8; ++j) bf[j] = wch[(lk * 8 + j) * 256 + n];
      acc1[nt] = MFMA16(af, bf, acc1[nt]);
    }
  }
  __syncthreads();
  #pragma unroll
  for (int nt = 0; nt < 4; ++nt) {
    int n = (wv * 4 + nt) * 16 + lr;
    float bb = gdb1[n];
    #pragma unroll
    for (int r = 0; r < 4; ++r)
      a1[(lk * 4 + r) * 256 + n] = (f16)fmaxf(acc1[nt][r] + bb, 0.0f);
  }

  f32x4 acc2[2];
  #pragma unroll
  for (int i = 0; i < 2; ++i) { f32x4 z = {0.f, 0.f, 0.f, 0.f}; acc2[i] = z; }
  for (int kt = 0; kt < 8; ++kt) {
    __syncthreads();
    for (int i = tid; i < 4096; i += 256) {
      int k = i >> 7, n = i & 127;
      wch[i] = (f16)gdw2[(kt * 32 + k) * 128 + n];
    }
    __syncthreads();
    f16x8 af = *(const f16x8*)((char*)a1 + lr * 512 + (kt * 32 + lk * 8) * 2);
    #pragma unroll
    for (int nt = 0; nt < 2; ++nt) {
      int n = (wv * 2 + nt) * 16 + lr;
      f16x8 bf;
      #pragma unroll
      for (int j = 0; j < 8; ++j) bf[j] = wch[(lk * 8 + j) * 128 + n];
      acc2[nt] = MFMA16(af, bf, acc2[nt]);
    }
  }
  __syncthreads();
  #pragma unroll
  for (int nt = 0; nt < 2; ++nt) {
    int n = (wv * 2 + nt) * 16 + lr;
    float bb = gdb2[n];
    #pragma unroll
    for (int r = 0; r < 4; ++r)
      a2[(lk * 4 + r) * 128 + n] = (f16)fmaxf(acc2[nt][r] + bb, 0.0f);
  }
  __syncthreads();

  for (int i = tid; i < 4096; i += 256) {
    int k = i >> 5, n = i & 31;
    w3s[i] = (n < 30) ? (f16)gdw3[k * 30 + n] : (f16)0.0f;
  }
  __syncthreads();
  if (wv < 2) {
    f32x4 acc3 = {0.f, 0.f, 0.f, 0.f};
    int n = wv * 16 + lr;
    #pragma unroll
    for (int kt = 0; kt < 4; ++kt) {
      f16x8 af = *(const f16x8*)((char*)a2 + lr * 256 + (kt * 32 + lk * 8) * 2);
      f16x8 bf;
      #pragma unroll
      for (int j = 0; j < 8; ++j) bf[j] = w3s[(kt * 32 + lk * 8 + j) * 32 + n];
      acc3 = MFMA16(af, bf, acc3);
    }
    if (n < 30) {
      float bb = gdb3[n];
      #pragma unroll
      for (int r = 0; r < 4; ++r) {
        float v = sigm(acc3[r] + bb);
        gout[(size_t)(bg + lk * 4 + r) * 30 + n] = v;
      }
    }
  }
}

extern "C" void kernel_launch(void* const* d_in, const int* in_sizes, int n_in,
                              void* d_out, int out_size, void* d_ws, size_t ws_size,
                              hipStream_t stream) {
  (void)in_sizes; (void)n_in; (void)out_size;
  const size_t W1OFF = 35651584;             // z: 32768*544*2
  const size_t W2OFF = W1OFF + 278528;       // w1t
  const size_t W3OFF = W2OFF + 65536;        // w2t
  const size_t NEED  = W3OFF + 8192;         // w3t
  if (ws_size >= NEED) {
    f16* wzp = (f16*)d_ws;
    f16* w1t = (f16*)((char*)d_ws + W1OFF);
    f16* w2t = (f16*)((char*)d_ws + W2OFF);
    f16* w3t = (f16*)((char*)d_ws + W3OFF);
    hwq_prep<<<256, 256, 0, stream>>>((const float*)d_in[8], (const float*)d_in[10],
                                      (const float*)d_in[12], w1t, w2t, w3t);
    hwq_rec<<<8192, 256, 0, stream>>>(
        (const float*)d_in[0], (const float*)d_in[1], (const float*)d_in[2],
        (const float*)d_in[3], (const float*)d_in[4], (const float*)d_in[5],
        (const float*)d_in[6], (const float*)d_in[7], wzp);
    hwq_dec<<<512, 256, 0, stream>>>(wzp, w1t, w2t, w3t,
                                     (const float*)d_in[9], (const float*)d_in[11],
                                     (const float*)d_in[13], (float*)d_out);
  } else {
    hwq_fused_mono<<<2048, 256, 0, stream>>>(
        (const float*)d_in[0],  (const float*)d_in[1],  (const float*)d_in[2],
        (const float*)d_in[3],  (const float*)d_in[4],  (const float*)d_in[5],
        (const float*)d_in[6],  (const float*)d_in[7],  (const float*)d_in[8],
        (const float*)d_in[9],  (const float*)d_in[10], (const float*)d_in[11],
        (const float*)d_in[12], (const float*)d_in[13], (float*)d_out);
  }
}

// Round 5
// 1060.145 us; speedup vs baseline: 1.0883x; 1.0883x over previous
//
#include <hip/hip_runtime.h>

typedef _Float16 f16;
typedef _Float16 f16x4 __attribute__((ext_vector_type(4)));
typedef _Float16 f16x8 __attribute__((ext_vector_type(8)));
typedef float f32x4 __attribute__((ext_vector_type(4)));

#define MFMA16(a, b, c) __builtin_amdgcn_mfma_f32_16x16x32_f16((a), (b), (c), 0, 0, 0)

__device__ __forceinline__ float rcp_(float x) { return __builtin_amdgcn_rcpf(x); }
__device__ __forceinline__ float sigm(float v) { return rcp_(1.0f + __expf(-v)); }
__device__ __forceinline__ float tanh_(float v) { return 1.0f - 2.0f * rcp_(__expf(2.0f * v) + 1.0f); }

// ======================= Kernel A: ConvLSTM recurrence =======================
// 256 threads = 4 waves = mg(0..1) x ng(0..1); 4 samples/block.
// Wave tile: M=64 (4 m-tiles of 16, m = ch*4+gate), N=32 (2 n-tiles: b=ng*2+nt, pos=lr).
// h-part: 9 tap-GEMMs K=32 (taps 3..8 A in registers, taps 0..2 streamed from LDS).
// x-part: xpad[4b][36 cell][4 sl] (3 ic + bias flag); MFMA1 K = tau*4+sl (tau 0..7),
//         MFMA2 tau=8 at k0..3 (A zero for k>=4 -> B upper garbage harmless).
//         Bias = conv_b at (tau=4, sl=3), xpad sl3 == 1 at interior cells.
// No im2col, no scattered scalar LDS ops in the hot loop except 8 h' b16 writes.
//
// LDS (bytes): hpad [4][36][36sl] 0..10368 (cell 72B) | xpad [4][36][4sl] 10368..11520
//              WS streamed taps [3 tp][128 m][36sl] 11520..39168 (also prologue scratch)
#define HP 0
#define XP 10368
#define WSO 11520
#define SMEMA 39168

extern "C" __global__ __launch_bounds__(256, 2)
void hwq_rec(const float* __restrict__ gx, const float* __restrict__ ghour,
             const float* __restrict__ gcw, const float* __restrict__ gcb,
             const float* __restrict__ ghw1, const float* __restrict__ ghb1,
             const float* __restrict__ ghw2, const float* __restrict__ ghb2,
             f16* __restrict__ wz)
{
  __shared__ __align__(16) char smem[SMEMA];
  const int tid = threadIdx.x;
  const int lane = tid & 63;
  const int wv = tid >> 6;
  const int mg = wv & 1;
  const int ng = wv >> 1;
  const int lr = lane & 15;
  const int lk = lane >> 4;
  const int bg = blockIdx.x << 2;
  const float* gxb = gx + (size_t)bg * 576;
  const int TOFF[9] = {0, 1, 2, 6, 7, 8, 12, 13, 14};
  const int pp0 = (lr >> 2) * 6 + (lr & 3);

  // ---- step 1: zero hpad+xpad; stage Ax1 table [128 m][32 k] into WS ----
  {
    float* za = (float*)smem;
    for (int i = tid; i < 2880; i += 256) za[i] = 0.0f;
    f16* axs = (f16*)(smem + WSO);
    for (int i = tid; i < 4096; i += 256) {
      int m = i >> 5, k = i & 31;
      int tau = k >> 2, sl = k & 3;
      int oc = ((m & 3) << 5) + (m >> 2);
      f16 v = (f16)0.0f;
      if (sl < 3) v = (f16)gcw[oc * 315 + sl * 9 + tau];
      else if (tau == 4) v = (f16)gcb[oc];
      axs[i] = v;
    }
    __syncthreads();
  }

  // ---- step 2: xpad bias/interior init + xpad(t=0); gather Ax1 ----
  f16x8 Ax1[4];
  {
    if (tid < 64) {
      int b = tid >> 4, p = tid & 15;
      int cell = ((p >> 2) + 1) * 6 + (p & 3) + 1;
      *(f16*)(smem + XP + b * 288 + cell * 8 + 6) = (f16)1.0f;   // sl3 = bias flag
    }
    if (tid < 192) {
      int b = tid / 48, rem = tid - b * 48;
      int p = rem & 15, ic = rem >> 4;
      int cell = ((p >> 2) + 1) * 6 + (p & 3) + 1;
      *(f16*)(smem + XP + b * 288 + cell * 8 + ic * 2) = (f16)gxb[(size_t)b * 576 + rem];
    }
    #pragma unroll
    for (int mt = 0; mt < 4; ++mt)
      Ax1[mt] = *(const f16x8*)(smem + WSO + ((mg * 64 + mt * 16 + lr) * 32 + lk * 8) * 2);
    __syncthreads();
  }

  // ---- step 3: register taps 3..8 via 4 staged chunks of 32 m-rows ----
  f16x8 Ah[6][4];
  {
    f16* wst = (f16*)(smem + WSO);   // [32 row][288 = ch*9+tap]
    #pragma unroll
    for (int c = 0; c < 4; ++c) {
      for (int i = tid; i < 9216; i += 256) {
        int mrow = i / 288, rem = i - mrow * 288;
        int m = c * 32 + mrow;
        int oc = ((m & 3) << 5) + (m >> 2);
        wst[i] = (f16)gcw[oc * 315 + 27 + rem];
      }
      __syncthreads();
      if (mg == (c >> 1)) {
        #pragma unroll
        for (int mtl = 0; mtl < 2; ++mtl) {
          int mt = (c & 1) * 2 + mtl;
          #pragma unroll
          for (int tp = 0; tp < 6; ++tp) {
            f16x8 f;
            #pragma unroll
            for (int j = 0; j < 8; ++j)
              f[j] = wst[(mtl * 16 + lr) * 288 + (lk * 8 + j) * 9 + (3 + tp)];
            Ah[tp][mt] = f;
          }
        }
      }
      __syncthreads();
    }
  }

  // ---- step 4: streamed taps 0..2 into persistent WS; Ax2 (tau=8) direct ----
  f16x8 Ax2[4];
  {
    f16* wl = (f16*)(smem + WSO);    // [3 tp][128 m][36 sl]
    for (int i = tid; i < 12288; i += 256) {
      int tp = i >> 12, rem = i & 4095;
      int m = rem >> 5, ch = rem & 31;
      int oc = ((m & 3) << 5) + (m >> 2);
      wl[tp * 4608 + m * 36 + ch] = (f16)gcw[oc * 315 + 27 + ch * 9 + tp];
    }
    #pragma unroll
    for (int mt = 0; mt < 4; ++mt) {
      int m = mg * 64 + mt * 16 + lr;
      int oc = ((m & 3) << 5) + (m >> 2);
      f16x8 f = {(f16)0, (f16)0, (f16)0, (f16)0, (f16)0, (f16)0, (f16)0, (f16)0};
      if (lk == 0) {
        f[0] = (f16)gcw[oc * 315 + 8];
        f[1] = (f16)gcw[oc * 315 + 17];
        f[2] = (f16)gcw[oc * 315 + 26];
      }
      Ax2[mt] = f;
    }
    __syncthreads();
  }

  // ---- hot-loop bases ----
  const int hb  = (ng * 2) * 2592 + pp0 * 72 + lk * 16;              // h B-frag (+nt*2592)
  const int xpb = XP + (ng * 2) * 288 + pp0 * 8;                     // x B-frag (+nt*288)
  const int wb  = (ng * 2) * 2592 + (pp0 + 7) * 72 + (mg * 16 + lk) * 2;  // h' (+nt*2592+mt*8)
  const int wa  = WSO + (mg * 64 + lr) * 72 + lk * 16;               // streamed A (+tp*9216+mt*1152)
  const int xo0 = TOFF[2 * lk] * 8;
  const int xo1 = TOFF[2 * lk + 1] * 8;

  const bool stg = tid < 192;
  const int sb = tid / 48, srem = tid - sb * 48;
  const int sp = srem & 15, sic = srem >> 4;
  const int xdst = XP + sb * 288 + (((sp >> 2) + 1) * 6 + (sp & 3) + 1) * 8 + sic * 2;
  const float* xsrc = gxb + (size_t)sb * 576 + srem;

  float cst[4][2];
  #pragma unroll
  for (int mt = 0; mt < 4; ++mt) { cst[mt][0] = 0.0f; cst[mt][1] = 0.0f; }

  for (int t = 0; t < 12; ++t) {
    float xv = 0.0f;
    if (t < 11 && stg) xv = xsrc[(t + 1) * 48];     // prefetch next x early

    f32x4 acc[4][2];
    #pragma unroll
    for (int mt = 0; mt < 4; ++mt)
      #pragma unroll
      for (int nt = 0; nt < 2; ++nt) { f32x4 z = {0.f, 0.f, 0.f, 0.f}; acc[mt][nt] = z; }

    // streamed taps 0..2 (A from LDS)
    #pragma unroll
    for (int tp = 0; tp < 3; ++tp) {
      const int to = TOFF[tp] * 72;
      f16x8 af[4];
      #pragma unroll
      for (int mt = 0; mt < 4; ++mt)
        af[mt] = *(const f16x8*)(smem + wa + tp * 9216 + mt * 1152);
      #pragma unroll
      for (int nt = 0; nt < 2; ++nt) {
        f16x8 bf = *(const f16x8*)(smem + hb + nt * 2592 + to);
        #pragma unroll
        for (int mt = 0; mt < 4; ++mt)
          acc[mt][nt] = MFMA16(af[mt], bf, acc[mt][nt]);
      }
    }
    // register taps 3..8
    #pragma unroll
    for (int tp = 0; tp < 6; ++tp) {
      const int to = TOFF[tp + 3] * 72;
      #pragma unroll
      for (int nt = 0; nt < 2; ++nt) {
        f16x8 bf = *(const f16x8*)(smem + hb + nt * 2592 + to);
        #pragma unroll
        for (int mt = 0; mt < 4; ++mt)
          acc[mt][nt] = MFMA16(Ah[tp][mt], bf, acc[mt][nt]);
      }
    }
    // x + bias: 2 MFMAs per (mt,nt), B from 3 ds_read_b64 per nt
    #pragma unroll
    for (int nt = 0; nt < 2; ++nt) {
      const int base = xpb + nt * 288;
      f16x4 lo = *(const f16x4*)(smem + base + xo0);
      f16x4 hi = *(const f16x4*)(smem + base + xo1);
      f16x8 bf1 = __builtin_shufflevector(lo, hi, 0, 1, 2, 3, 4, 5, 6, 7);
      f16x4 l8 = *(const f16x4*)(smem + base + 112);            // TOFF[8]*8
      f16x8 bf2 = __builtin_shufflevector(l8, l8, 0, 1, 2, 3, 0, 1, 2, 3);
      #pragma unroll
      for (int mt = 0; mt < 4; ++mt) {
        acc[mt][nt] = MFMA16(Ax1[mt], bf1, acc[mt][nt]);
        acc[mt][nt] = MFMA16(Ax2[mt], bf2, acc[mt][nt]);
      }
    }
    __syncthreads();   // all hpad/xpad reads done

    // cell update in-register (acc[mt][nt] = gates i,f,o,g of one (ch,b,pos))
    #pragma unroll
    for (int mt = 0; mt < 4; ++mt) {
      #pragma unroll
      for (int nt = 0; nt < 2; ++nt) {
        float ig = sigm(acc[mt][nt][0]);
        float fg = sigm(acc[mt][nt][1]);
        float og = sigm(acc[mt][nt][2]);
        float gg = tanh_(acc[mt][nt][3]);
        float cn = fg * cst[mt][nt] + ig * gg;
        cst[mt][nt] = cn;
        f16 h = (f16)(og * tanh_(cn));
        if (t < 11) {
          *(f16*)(smem + wb + nt * 2592 + mt * 8) = h;
        } else {
          int ch = mg * 16 + mt * 4 + lk;
          wz[(size_t)(bg + ng * 2 + nt) * 544 + ch * 16 + lr] = h;
        }
      }
    }
    if (t < 11) {
      if (stg) *(f16*)(smem + xdst) = (f16)xv;
    } else if (tid < 128) {
      int b = tid >> 5, k2 = tid & 31;
      float h0 = ghour[bg + b];
      float a = ghb2[k2];
      #pragma unroll
      for (int ii = 0; ii < 16; ++ii) {
        float u = fmaxf(h0 * ghw1[ii] + ghb1[ii], 0.0f);
        a += u * ghw2[ii * 32 + k2];
      }
      wz[(size_t)(bg + b) * 544 + 512 + k2] = (f16)a;
    }
    __syncthreads();
  }
}

// ======================= prep: weight transpose fp32->f16 =======================
extern "C" __global__ void hwq_prep(const float* __restrict__ gdw1,
                                    const float* __restrict__ gdw2,
                                    const float* __restrict__ gdw3,
                                    f16* __restrict__ w1t, f16* __restrict__ w2t,
                                    f16* __restrict__ w3t)
{
  int i0 = blockIdx.x * 256 + threadIdx.x;
  int stride = gridDim.x * 256;
  for (int idx = i0; idx < 139264; idx += stride) {
    int n = idx / 544, k = idx - n * 544;
    w1t[idx] = (f16)gdw1[k * 256 + n];
  }
  for (int idx = i0; idx < 32768; idx += stride) {
    int n = idx >> 8, k = idx & 255;
    w2t[idx] = (f16)gdw2[k * 128 + n];
  }
  for (int idx = i0; idx < 4096; idx += stride) {
    int n = idx >> 7, k = idx & 127;
    w3t[idx] = (n < 30) ? (f16)gdw3[k * 30 + n] : (f16)0.0f;
  }
}

// ======================= Kernel B: decoder MLP =======================
extern "C" __global__ __launch_bounds__(256, 2)
void hwq_dec(const f16* __restrict__ wz, const f16* __restrict__ w1t,
             const f16* __restrict__ w2t, const f16* __restrict__ w3t,
             const float* __restrict__ gdb1, const float* __restrict__ gdb2,
             const float* __restrict__ gdb3, float* __restrict__ gout)
{
  __shared__ __align__(16) char smem[55296];
  f16* a1 = (f16*)smem;               // [64][280]
  f16* a2 = (f16*)(smem + 35840);     // [64][152]
  const int tid = threadIdx.x;
  const int lane = tid & 63;
  const int wv = tid >> 6;
  const int lr = lane & 15;
  const int lk = lane >> 4;
  const int s0 = blockIdx.x << 6;

  f32x4 acc1[4][4];
  #pragma unroll
  for (int nt = 0; nt < 4; ++nt) {
    float bb = gdb1[wv * 64 + nt * 16 + lr];
    f32x4 bv = {bb, bb, bb, bb};
    #pragma unroll
    for (int mt = 0; mt < 4; ++mt) acc1[mt][nt] = bv;
  }
  for (int kt = 0; kt < 17; ++kt) {
    f16x8 af[4];
    #pragma unroll
    for (int mt = 0; mt < 4; ++mt)
      af[mt] = *(const f16x8*)(wz + (size_t)(s0 + mt * 16 + lr) * 544 + kt * 32 + lk * 8);
    #pragma unroll
    for (int nt = 0; nt < 4; ++nt) {
      f16x8 bf = *(const f16x8*)(w1t + (size_t)(wv * 64 + nt * 16 + lr) * 544 + kt * 32 + lk * 8);
      #pragma unroll
      for (int mt = 0; mt < 4; ++mt)
        acc1[mt][nt] = MFMA16(af[mt], bf, acc1[mt][nt]);
    }
  }
  #pragma unroll
  for (int mt = 0; mt < 4; ++mt)
    #pragma unroll
    for (int nt = 0; nt < 4; ++nt) {
      int n = wv * 64 + nt * 16 + lr;
      #pragma unroll
      for (int r = 0; r < 4; ++r)
        a1[(mt * 16 + lk * 4 + r) * 280 + n] = (f16)fmaxf(acc1[mt][nt][r], 0.0f);
    }
  __syncthreads();

  f32x4 acc2[4][2];
  #pragma unroll
  for (int nt = 0; nt < 2; ++nt) {
    float bb = gdb2[wv * 32 + nt * 16 + lr];
    f32x4 bv = {bb, bb, bb, bb};
    #pragma unroll
    for (int mt = 0; mt < 4; ++mt) acc2[mt][nt] = bv;
  }
  for (int kt = 0; kt < 8; ++kt) {
    f16x8 af[4];
    #pragma unroll
    for (int mt = 0; mt < 4; ++mt)
      af[mt] = *(const f16x8*)(a1 + (mt * 16 + lr) * 280 + kt * 32 + lk * 8);
    #pragma unroll
    for (int nt = 0; nt < 2; ++nt) {
      f16x8 bf = *(const f16x8*)(w2t + (size_t)(wv * 32 + nt * 16 + lr) * 256 + kt * 32 + lk * 8);
      #pragma unroll
      for (int mt = 0; mt < 4; ++mt)
        acc2[mt][nt] = MFMA16(af[mt], bf, acc2[mt][nt]);
    }
  }
  __syncthreads();
  #pragma unroll
  for (int mt = 0; mt < 4; ++mt)
    #pragma unroll
    for (int nt = 0; nt < 2; ++nt) {
      int n = wv * 32 + nt * 16 + lr;
      #pragma unroll
      for (int r = 0; r < 4; ++r)
        a2[(mt * 16 + lk * 4 + r) * 152 + n] = (f16)fmaxf(acc2[mt][nt][r], 0.0f);
    }
  __syncthreads();

  if (wv < 2) {
    int n = wv * 16 + lr;
    float bb = (n < 30) ? gdb3[n] : 0.0f;
    f32x4 acc3[4];
    #pragma unroll
    for (int mt = 0; mt < 4; ++mt) { f32x4 bv = {bb, bb, bb, bb}; acc3[mt] = bv; }
    #pragma unroll
    for (int kt = 0; kt < 4; ++kt) {
      f16x8 bf = *(const f16x8*)(w3t + n * 128 + kt * 32 + lk * 8);
      #pragma unroll
      for (int mt = 0; mt < 4; ++mt) {
        f16x8 af = *(const f16x8*)(a2 + (mt * 16 + lr) * 152 + kt * 32 + lk * 8);
        acc3[mt] = MFMA16(af, bf, acc3[mt]);
      }
    }
    if (n < 30) {
      #pragma unroll
      for (int mt = 0; mt < 4; ++mt)
        #pragma unroll
        for (int r = 0; r < 4; ++r)
          gout[(size_t)(s0 + mt * 16 + lk * 4 + r) * 30 + n] = sigm(acc3[mt][r]);
    }
  }
}

// ======================= Fallback: monolithic kernel (R1) =======================
typedef _Float16 f16x4m __attribute__((ext_vector_type(4)));
#define OFF_B 46080
#define SMEM_BYTES (46080 + 17408)

extern "C" __global__ __launch_bounds__(256, 1)
void hwq_fused_mono(const float* __restrict__ gx, const float* __restrict__ ghour,
               const float* __restrict__ gcw, const float* __restrict__ gcb,
               const float* __restrict__ ghw1, const float* __restrict__ ghb1,
               const float* __restrict__ ghw2, const float* __restrict__ ghb2,
               const float* __restrict__ gdw1, const float* __restrict__ gdb1,
               const float* __restrict__ gdw2, const float* __restrict__ gdb2,
               const float* __restrict__ gdw3, const float* __restrict__ gdb3,
               float* __restrict__ gout)
{
  __shared__ __align__(16) char smem[SMEM_BYTES];
  const int tid = threadIdx.x;
  const int lane = tid & 63;
  const int wv = tid >> 6;
  const int mg = wv & 1;
  const int ng = wv >> 1;
  const int lr = lane & 15;
  const int lk = lane >> 4;
  const int bg = blockIdx.x << 4;

  f16x8 Ah[9][4];
  {
    f16* wst = (f16*)(smem);
    #pragma unroll
    for (int c = 0; c < 2; ++c) {
      __syncthreads();
      for (int i = tid; i < 18432; i += 256) {
        int oc = i / 288, rem = i - oc * 288;
        wst[i] = (f16)gcw[(c * 64 + oc) * 315 + 27 + rem];
      }
      __syncthreads();
      #pragma unroll
      for (int g = 0; g < 2; ++g) {
        int ocl = g * 32 + mg * 16 + lr;
        #pragma unroll
        for (int tap = 0; tap < 9; ++tap) {
          f16x8 f;
          #pragma unroll
          for (int j = 0; j < 8; ++j)
            f[j] = wst[ocl * 288 + (lk * 8 + j) * 9 + tap];
          Ah[tap][c * 2 + g] = f;
        }
      }
    }
  }
  f16x8 Ax[4];
  {
    f16* xw = (f16*)(smem + OFF_B);
    __syncthreads();
    for (int i = tid; i < 3456; i += 256) {
      int oc = i / 27, rem = i - oc * 27;
      xw[i] = (f16)gcw[oc * 315 + rem];
    }
    __syncthreads();
    #pragma unroll
    for (int mt = 0; mt < 4; ++mt) {
      int oc = mt * 32 + mg * 16 + lr;
      f16x8 f;
      #pragma unroll
      for (int j = 0; j < 8; ++j) {
        int k = lk * 8 + j;
        int tap = (k * 11) >> 5;
        int ic = k - 3 * tap;
        f16 v = (f16)0.0f;
        if (k < 27) v = xw[oc * 27 + ic * 9 + tap];
        f[j] = v;
      }
      Ax[mt] = f;
    }
    __syncthreads();
  }

  float bias[4][4];
  #pragma unroll
  for (int mt = 0; mt < 4; ++mt)
    #pragma unroll
    for (int r = 0; r < 4; ++r)
      bias[mt][r] = gcb[mt * 32 + mg * 16 + lk * 4 + r];

  {
    float* za = (float*)smem;
    for (int i = tid; i < 11520; i += 256) za[i] = 0.0f;
    float* zb = (float*)(smem + OFF_B);
    for (int i = tid; i < 1152; i += 256) zb[i] = 0.0f;
    __syncthreads();
    for (int i = tid; i < 768; i += 256) {
      int b = i / 48, rem = i - b * 48;
      int pos = rem & 15;
      int ic = rem >> 4;
      int pp = (pos >> 2) * 6 + (pos & 3) + 7;
      *(f16*)(smem + OFF_B + b * 288 + pp * 8 + ic * 2) =
          (f16)gx[(size_t)(bg + b) * 576 + rem];
    }
    __syncthreads();
  }

  int hbase[8], xbase[8], wbase[8];
  #pragma unroll
  for (int nt = 0; nt < 8; ++nt) {
    int n = ng * 128 + nt * 16 + lr;
    int b = n >> 4, pos = n & 15;
    int pp0 = (pos >> 2) * 6 + (pos & 3);
    hbase[nt] = b * 2880 + pp0 * 80 + lk * 16;
    xbase[nt] = OFF_B + b * 288 + pp0 * 8;
    wbase[nt] = b * 2880 + (pp0 + 7) * 80 + (mg * 16 + lk * 4) * 2;
  }
  int xoff[8], xval[8];
  #pragma unroll
  for (int j = 0; j < 8; ++j) {
    int k = lk * 8 + j;
    int tap = (k * 11) >> 5;
    int ic = k - 3 * tap;
    xoff[j] = ((tap / 3) * 6 + (tap % 3)) * 8 + ic * 2;
    xval[j] = (k < 27);
  }

  const int TOFF[9] = {0, 1, 2, 6, 7, 8, 12, 13, 14};

  f32x4 cst[8];
  #pragma unroll
  for (int nt = 0; nt < 8; ++nt) { f32x4 z = {0.f, 0.f, 0.f, 0.f}; cst[nt] = z; }

  for (int t = 0; t < 12; ++t) {
    f32x4 acc[4][8];
    #pragma unroll
    for (int mt = 0; mt < 4; ++mt) {
      f32x4 bi = {bias[mt][0], bias[mt][1], bias[mt][2], bias[mt][3]};
      #pragma unroll
      for (int nt = 0; nt < 8; ++nt) acc[mt][nt] = bi;
    }
    #pragma unroll
    for (int tap = 0; tap < 9; ++tap) {
      #pragma unroll
      for (int nt = 0; nt < 8; ++nt) {
        f16x8 bf = *(const f16x8*)(smem + hbase[nt] + TOFF[tap] * 80);
        #pragma unroll
        for (int mt = 0; mt < 4; ++mt)
          acc[mt][nt] = MFMA16(Ah[tap][mt], bf, acc[mt][nt]);
      }
    }
    #pragma unroll
    for (int nt = 0; nt < 8; ++nt) {
      f16x8 bf;
      #pragma unroll
      for (int j = 0; j < 8; ++j) {
        int a = xval[j] ? (xbase[nt] + xoff[j]) : OFF_B;
        bf[j] = *(const f16*)(smem + a);
      }
      #pragma unroll
      for (int mt = 0; mt < 4; ++mt)
        acc[mt][nt] = MFMA16(Ax[mt], bf, acc[mt][nt]);
    }
    __syncthreads();

    #pragma unroll
    for (int nt = 0; nt < 8; ++nt) {
      f16 hh[4];
      #pragma unroll
      for (int r = 0; r < 4; ++r) {
        float ig = sigm(acc[0][nt][r]);
        float fg = sigm(acc[1][nt][r]);
        float og = sigm(acc[2][nt][r]);
        float gg = tanh_(acc[3][nt][r]);
        float cn = fg * cst[nt][r] + ig * gg;
        cst[nt][r] = cn;
        hh[r] = (f16)(og * tanh_(cn));
      }
      if (t < 11) {
        f16x4m hv = {hh[0], hh[1], hh[2], hh[3]};
        *(f16x4m*)(smem + wbase[nt]) = hv;
      } else {
        int n = ng * 128 + nt * 16 + lr;
        int b = n >> 4, pos = n & 15;
        int ch0 = mg * 16 + lk * 4;
        #pragma unroll
        for (int r = 0; r < 4; ++r)
          *(f16*)(smem + OFF_B + b * 1088 + (ch0 + r) * 32 + pos * 2) = hh[r];
      }
    }
    if (t < 11) {
      for (int i = tid; i < 768; i += 256) {
        int b = i / 48, rem = i - b * 48;
        int pos = rem & 15;
        int ic = rem >> 4;
        int pp = (pos >> 2) * 6 + (pos & 3) + 7;
        *(f16*)(smem + OFF_B + b * 288 + pp * 8 + ic * 2) =
            (f16)gx[(size_t)(bg + b) * 576 + (t + 1) * 48 + rem];
      }
    } else {
      for (int i = tid; i < 512; i += 256) {
        int b = i >> 5, k2 = i & 31;
        float h0 = ghour[bg + b];
        float a = ghb2[k2];
        #pragma unroll
        for (int ii = 0; ii < 16; ++ii) {
          float u = fmaxf(h0 * ghw1[ii] + ghb1[ii], 0.0f);
          a += u * ghw2[ii * 32 + k2];
        }
        *(f16*)(smem + OFF_B + b * 1088 + (512 + k2) * 2) = (f16)a;
      }
    }
    __syncthreads();
  }

  f16* zz  = (f16*)(smem + OFF_B);
  f16* wch = (f16*)(smem);
  f16* a1  = (f16*)(smem + 16384);
  f16* a2  = (f16*)(smem + 24576);
  f16* w3s = (f16*)(smem + 28672);

  f32x4 acc1[4];
  #pragma unroll
  for (int i = 0; i < 4; ++i) { f32x4 z = {0.f, 0.f, 0.f, 0.f}; acc1[i] = z; }
  for (int kt = 0; kt < 17; ++kt) {
    __syncthreads();
    for (int i = tid; i < 8192; i += 256) {
      int k = i >> 8, n = i & 255;
      wch[i] = (f16)gdw1[(kt * 32 + k) * 256 + n];
    }
    __syncthreads();
    f16x8 af = *(const f16x8*)((char*)zz + lr * 1088 + (kt * 32 + lk * 8) * 2);
    #pragma unroll
    for (int nt = 0; nt < 4; ++nt) {
      int n = (wv * 4 + nt) * 16 + lr;
      f16x8 bf;
      #pragma unroll
      for (int j = 0; j < 8; ++j) bf[j] = wch[(lk * 8 + j) * 256 + n];
      acc1[nt] = MFMA16(af, bf, acc1[nt]);
    }
  }
  __syncthreads();
  #pragma unroll
  for (int nt = 0; nt < 4; ++nt) {
    int n = (wv * 4 + nt) * 16 + lr;
    float bb = gdb1[n];
    #pragma unroll
    for (int r = 0; r < 4; ++r)
      a1[(lk * 4 + r) * 256 + n] = (f16)fmaxf(acc1[nt][r] + bb, 0.0f);
  }

  f32x4 acc2[2];
  #pragma unroll
  for (int i = 0; i < 2; ++i) { f32x4 z = {0.f, 0.f, 0.f, 0.f}; acc2[i] = z; }
  for (int kt = 0; kt < 8; ++kt) {
    __syncthreads();
    for (int i = tid; i < 4096; i += 256) {
      int k = i >> 7, n = i & 127;
      wch[i] = (f16)gdw2[(kt * 32 + k) * 128 + n];
    }
    __syncthreads();
    f16x8 af = *(const f16x8*)((char*)a1 + lr * 512 + (kt * 32 + lk * 8) * 2);
    #pragma unroll
    for (int nt = 0; nt < 2; ++nt) {
      int n = (wv * 2 + nt) * 16 + lr;
      f16x8 bf;
      #pragma unroll
      for (int j = 0; j < 8; ++j) bf[j] = wch[(lk * 8 + j) * 128 + n];
      acc2[nt] = MFMA16(af, bf, acc2[nt]);
    }
  }
  __syncthreads();
  #pragma unroll
  for (int nt = 0; nt < 2; ++nt) {
    int n = (wv * 2 + nt) * 16 + lr;
    float bb = gdb2[n];
    #pragma unroll
    for (int r = 0; r < 4; ++r)
      a2[(lk * 4 + r) * 128 + n] = (f16)fmaxf(acc2[nt][r] + bb, 0.0f);
  }
  __syncthreads();

  for (int i = tid; i < 4096; i += 256) {
    int k = i >> 5, n = i & 31;
    w3s[i] = (n < 30) ? (f16)gdw3[k * 30 + n] : (f16)0.0f;
  }
  __syncthreads();
  if (wv < 2) {
    f32x4 acc3 = {0.f, 0.f, 0.f, 0.f};
    int n = wv * 16 + lr;
    #pragma unroll
    for (int kt = 0; kt < 4; ++kt) {
      f16x8 af = *(const f16x8*)((char*)a2 + lr * 256 + (kt * 32 + lk * 8) * 2);
      f16x8 bf;
      #pragma unroll
      for (int j = 0; j < 8; ++j) bf[j] = w3s[(kt * 32 + lk * 8 + j) * 32 + n];
      acc3 = MFMA16(af, bf, acc3);
    }
    if (n < 30) {
      float bb = gdb3[n];
      #pragma unroll
      for (int r = 0; r < 4; ++r) {
        float v = sigm(acc3[r] + bb);
        gout[(size_t)(bg + lk * 4 + r) * 30 + n] = v;
      }
    }
  }
}

extern "C" void kernel_launch(void* const* d_in, const int* in_sizes, int n_in,
                              void* d_out, int out_size, void* d_ws, size_t ws_size,
                              hipStream_t stream) {
  (void)in_sizes; (void)n_in; (void)out_size;
  const size_t W1OFF = 35651584;             // z: 32768*544*2
  const size_t W2OFF = W1OFF + 278528;       // w1t
  const size_t W3OFF = W2OFF + 65536;        // w2t
  const size_t NEED  = W3OFF + 8192;         // w3t
  if (ws_size >= NEED) {
    f16* wzp = (f16*)d_ws;
    f16* w1t = (f16*)((char*)d_ws + W1OFF);
    f16* w2t = (f16*)((char*)d_ws + W2OFF);
    f16* w3t = (f16*)((char*)d_ws + W3OFF);
    hwq_prep<<<256, 256, 0, stream>>>((const float*)d_in[8], (const float*)d_in[10],
                                      (const float*)d_in[12], w1t, w2t, w3t);
    hwq_rec<<<8192, 256, 0, stream>>>(
        (const float*)d_in[0], (const float*)d_in[1], (const float*)d_in[2],
        (const float*)d_in[3], (const float*)d_in[4], (const float*)d_in[5],
        (const float*)d_in[6], (const float*)d_in[7], wzp);
    hwq_dec<<<512, 256, 0, stream>>>(wzp, w1t, w2t, w3t,
                                     (const float*)d_in[9], (const float*)d_in[11],
                                     (const float*)d_in[13], (float*)d_out);
  } else {
    hwq_fused_mono<<<2048, 256, 0, stream>>>(
        (const float*)d_in[0],  (const float*)d_in[1],  (const float*)d_in[2],
        (const float*)d_in[3],  (const float*)d_in[4],  (const float*)d_in[5],
        (const float*)d_in[6],  (const float*)d_in[7],  (const float*)d_in[8],
        (const float*)d_in[9],  (const float*)d_in[10], (const float*)d_in[11],
        (const float*)d_in[12], (const float*)d_in[13], (float*)d_out);
  }
}

// Round 6
// 808.118 us; speedup vs baseline: 1.4277x; 1.3119x over previous
//
#include <hip/hip_runtime.h>

typedef _Float16 f16;
typedef _Float16 f16x4 __attribute__((ext_vector_type(4)));
typedef _Float16 f16x8 __attribute__((ext_vector_type(8)));
typedef float f32x2 __attribute__((ext_vector_type(2)));
typedef float f32x4 __attribute__((ext_vector_type(4)));

#define MFMA16(a, b, c) __builtin_amdgcn_mfma_f32_16x16x32_f16((a), (b), (c), 0, 0, 0)

__device__ __forceinline__ float rcp_(float x) { return __builtin_amdgcn_rcpf(x); }
__device__ __forceinline__ float sigm(float v) { return rcp_(1.0f + __expf(-v)); }
__device__ __forceinline__ float tanh_(float v) { return 1.0f - 2.0f * rcp_(__expf(2.0f * v) + 1.0f); }

// ======================= Kernel A: persistent ConvLSTM recurrence ==============
// Grid 1024 blocks (4/CU), each sweeps 8 sample-groups of 4 samples; conv weights
// staged ONCE per block (registers + LDS), amortized over 96 t-steps.
// 256 threads = 4 waves; wave mg owns M=32 (m = ch*4+gate, ch in [mg*8,mg*8+8)),
// all N=64 (nt = sample, pos = lr). Taps 0..2 A streamed from LDS; taps 3..8 in
// registers; x-part via padded xpad (no im2col), bias folded as xpad sl3 channel.
//
// LDS: hpad [4 b][36 cell][36 sl f16] 0..10368 (cell 72B) | xpad [4][36][4sl] ..11520
//      WS [3 tp][128 m][36 sl] 11520..39168 (prologue scratch too)
#define XP 10368
#define WSO 11520
#define SMEMA 39168
#define NGRP 8192
#define GRID_REC 1024

extern "C" __global__ __launch_bounds__(256, 4)
void hwq_rec(const float* __restrict__ gx, const float* __restrict__ ghour,
             const float* __restrict__ gcw, const float* __restrict__ gcb,
             const float* __restrict__ ghw1, const float* __restrict__ ghb1,
             const float* __restrict__ ghw2, const float* __restrict__ ghb2,
             f16* __restrict__ wz)
{
  __shared__ __align__(16) char smem[SMEMA];
  const int tid = threadIdx.x;
  const int lane = tid & 63;
  const int mg = tid >> 6;              // wave id = channel group
  const int lr = lane & 15;
  const int lk = lane >> 4;
  const int TOFF[9] = {0, 1, 2, 6, 7, 8, 12, 13, 14};
  const int pp0 = (lr >> 2) * 6 + (lr & 3);

  // ---- prologue 1: zero hpad+xpad; stage Ax1 table [128 m][32 k] ----
  {
    float* za = (float*)smem;
    for (int i = tid; i < 2880; i += 256) za[i] = 0.0f;
    f16* axs = (f16*)(smem + WSO);
    for (int i = tid; i < 4096; i += 256) {
      int m = i >> 5, k = i & 31;
      int tau = k >> 2, sl = k & 3;
      int oc = ((m & 3) << 5) + (m >> 2);
      f16 v = (f16)0.0f;
      if (sl < 3) v = (f16)gcw[oc * 315 + sl * 9 + tau];
      else if (tau == 4) v = (f16)gcb[oc];
      axs[i] = v;
    }
    __syncthreads();
  }
  // ---- prologue 2: xpad bias flags; gather Ax1 ----
  f16x8 Ax1[2];
  {
    if (tid < 64) {
      int b = tid >> 4, p = tid & 15;
      int cell = ((p >> 2) + 1) * 6 + (p & 3) + 1;
      *(f16*)(smem + XP + b * 288 + cell * 8 + 6) = (f16)1.0f;
    }
    #pragma unroll
    for (int mti = 0; mti < 2; ++mti)
      Ax1[mti] = *(const f16x8*)(smem + WSO + (mg * 32 + mti * 16 + lr) * 64 + lk * 16);
    __syncthreads();
  }
  // ---- prologue 3: register taps 3..8 via 4 staged chunks of 32 m-rows ----
  f16x8 Ah[6][2];
  {
    f16* wst = (f16*)(smem + WSO);   // [32 row][288 = ch*9+tap]
    #pragma unroll
    for (int c = 0; c < 4; ++c) {
      for (int i = tid; i < 9216; i += 256) {
        int mrow = i / 288, rem = i - mrow * 288;
        int m = c * 32 + mrow;
        int oc = ((m & 3) << 5) + (m >> 2);
        wst[i] = (f16)gcw[oc * 315 + 27 + rem];
      }
      __syncthreads();
      if (mg == c) {
        #pragma unroll
        for (int mti = 0; mti < 2; ++mti)
          #pragma unroll
          for (int tp = 0; tp < 6; ++tp) {
            f16x8 f;
            #pragma unroll
            for (int j = 0; j < 8; ++j)
              f[j] = wst[(mti * 16 + lr) * 288 + (lk * 8 + j) * 9 + (3 + tp)];
            Ah[tp][mti] = f;
          }
      }
      __syncthreads();
    }
  }
  // ---- prologue 4: streamed taps 0..2 into WS [3][128 m][36 sl]; Ax2 ----
  f16x8 Ax2[2];
  {
    f16* wl = (f16*)(smem + WSO);
    for (int i = tid; i < 12288; i += 256) {
      int tp = i >> 12, rem = i & 4095;
      int m = rem >> 5, ch = rem & 31;
      int oc = ((m & 3) << 5) + (m >> 2);
      wl[tp * 4608 + m * 36 + ch] = (f16)gcw[oc * 315 + 27 + ch * 9 + tp];
    }
    #pragma unroll
    for (int mti = 0; mti < 2; ++mti) {
      int m = mg * 32 + mti * 16 + lr;
      int oc = ((m & 3) << 5) + (m >> 2);
      f16x8 f = {(f16)0, (f16)0, (f16)0, (f16)0, (f16)0, (f16)0, (f16)0, (f16)0};
      if (lk == 0) {
        f[0] = (f16)gcw[oc * 315 + 8];
        f[1] = (f16)gcw[oc * 315 + 17];
        f[2] = (f16)gcw[oc * 315 + 26];
      }
      Ax2[mti] = f;
    }
    __syncthreads();
  }

  // ---- hot-loop bases (group-invariant) ----
  const int hb  = pp0 * 72 + lk * 16;                        // + nt*2592
  const int xpb = XP + pp0 * 8;                              // + nt*288
  const int wb  = (pp0 + 7) * 72 + (mg * 8 + lk) * 2;        // + nt*2592 + mti*8
  const int wa  = WSO + (mg * 32 + lr) * 72 + lk * 16;       // + tp*9216 + mti*1152
  const int xo0 = TOFF[2 * lk] * 8;
  const int xo1 = TOFF[2 * lk + 1] * 8;
  const bool stg = tid < 192;
  const int sb = tid / 48, srem = tid - sb * 48;
  const int sp = srem & 15, sic = srem >> 4;
  const int xdst = XP + sb * 288 + (((sp >> 2) + 1) * 6 + (sp & 3) + 1) * 8 + sic * 2;
  const int zb_ = tid >> 6, zc16 = (tid >> 2) & 15, zpart = tid & 3;
  const int zaddr = zb_ * 2592 + ((zc16 >> 2) * 6 + (zc16 & 3) + 7) * 72 + zpart * 16;

  for (int grp = blockIdx.x; grp < NGRP; grp += GRID_REC) {
    const int bg = grp << 2;
    const float* gxb = gx + (size_t)bg * 576;
    const float* xsrc = gxb + (size_t)sb * 576 + srem;

    // group re-init: zero hpad interior (h0=c0=0), stage xpad(t=0)
    {
      f32x2 z2 = {0.f, 0.f};
      *(f32x2*)(smem + zaddr) = z2;
      *(f32x2*)(smem + zaddr + 8) = z2;
    }
    if (stg) *(f16*)(smem + xdst) = (f16)xsrc[0];
    float cst[2][4];
    #pragma unroll
    for (int mti = 0; mti < 2; ++mti)
      #pragma unroll
      for (int nt = 0; nt < 4; ++nt) cst[mti][nt] = 0.0f;
    __syncthreads();

    for (int t = 0; t < 12; ++t) {
      float xv = 0.0f;
      if (t < 11 && stg) xv = xsrc[(t + 1) * 48];   // prefetch next x early

      f32x4 acc[2][4];
      #pragma unroll
      for (int mti = 0; mti < 2; ++mti)
        #pragma unroll
        for (int nt = 0; nt < 4; ++nt) { f32x4 z = {0.f, 0.f, 0.f, 0.f}; acc[mti][nt] = z; }

      // streamed taps 0..2 (A from LDS)
      #pragma unroll
      for (int tp = 0; tp < 3; ++tp) {
        const int to = TOFF[tp] * 72;
        f16x8 af0 = *(const f16x8*)(smem + wa + tp * 9216);
        f16x8 af1 = *(const f16x8*)(smem + wa + tp * 9216 + 1152);
        #pragma unroll
        for (int nt = 0; nt < 4; ++nt) {
          f16x8 bf = *(const f16x8*)(smem + hb + nt * 2592 + to);
          acc[0][nt] = MFMA16(af0, bf, acc[0][nt]);
          acc[1][nt] = MFMA16(af1, bf, acc[1][nt]);
        }
      }
      // register taps 3..8
      #pragma unroll
      for (int tp = 0; tp < 6; ++tp) {
        const int to = TOFF[tp + 3] * 72;
        #pragma unroll
        for (int nt = 0; nt < 4; ++nt) {
          f16x8 bf = *(const f16x8*)(smem + hb + nt * 2592 + to);
          acc[0][nt] = MFMA16(Ah[tp][0], bf, acc[0][nt]);
          acc[1][nt] = MFMA16(Ah[tp][1], bf, acc[1][nt]);
        }
      }
      // x + bias
      #pragma unroll
      for (int nt = 0; nt < 4; ++nt) {
        const int base = xpb + nt * 288;
        f16x4 lo = *(const f16x4*)(smem + base + xo0);
        f16x4 hi = *(const f16x4*)(smem + base + xo1);
        f16x8 bf1 = __builtin_shufflevector(lo, hi, 0, 1, 2, 3, 4, 5, 6, 7);
        f16x4 l8 = *(const f16x4*)(smem + base + 112);
        f16x8 bf2 = __builtin_shufflevector(l8, l8, 0, 1, 2, 3, 0, 1, 2, 3);
        acc[0][nt] = MFMA16(Ax1[0], bf1, acc[0][nt]);
        acc[1][nt] = MFMA16(Ax1[1], bf1, acc[1][nt]);
        acc[0][nt] = MFMA16(Ax2[0], bf2, acc[0][nt]);
        acc[1][nt] = MFMA16(Ax2[1], bf2, acc[1][nt]);
      }
      __syncthreads();   // all hpad/xpad reads done

      // cell update in-register
      #pragma unroll
      for (int mti = 0; mti < 2; ++mti) {
        #pragma unroll
        for (int nt = 0; nt < 4; ++nt) {
          float ig = sigm(acc[mti][nt][0]);
          float fg = sigm(acc[mti][nt][1]);
          float og = sigm(acc[mti][nt][2]);
          float gg = tanh_(acc[mti][nt][3]);
          float cn = fg * cst[mti][nt] + ig * gg;
          cst[mti][nt] = cn;
          f16 h = (f16)(og * tanh_(cn));
          if (t < 11) {
            *(f16*)(smem + wb + nt * 2592 + mti * 8) = h;
          } else {
            int ch = mg * 8 + mti * 4 + lk;
            wz[(size_t)(bg + nt) * 544 + ch * 16 + lr] = h;
          }
        }
      }
      if (t < 11) {
        if (stg) *(f16*)(smem + xdst) = (f16)xv;
      } else if (tid < 128) {
        int b = tid >> 5, k2 = tid & 31;
        float h0 = ghour[bg + b];
        float a = ghb2[k2];
        #pragma unroll
        for (int ii = 0; ii < 16; ++ii) {
          float u = fmaxf(h0 * ghw1[ii] + ghb1[ii], 0.0f);
          a += u * ghw2[ii * 32 + k2];
        }
        wz[(size_t)(bg + b) * 544 + 512 + k2] = (f16)a;
      }
      __syncthreads();
    }
  }
}

// ======================= prep: weight transpose fp32->f16 =======================
extern "C" __global__ void hwq_prep(const float* __restrict__ gdw1,
                                    const float* __restrict__ gdw2,
                                    const float* __restrict__ gdw3,
                                    f16* __restrict__ w1t, f16* __restrict__ w2t,
                                    f16* __restrict__ w3t)
{
  int i0 = blockIdx.x * 256 + threadIdx.x;
  int stride = gridDim.x * 256;
  for (int idx = i0; idx < 139264; idx += stride) {
    int n = idx / 544, k = idx - n * 544;
    w1t[idx] = (f16)gdw1[k * 256 + n];
  }
  for (int idx = i0; idx < 32768; idx += stride) {
    int n = idx >> 8, k = idx & 255;
    w2t[idx] = (f16)gdw2[k * 128 + n];
  }
  for (int idx = i0; idx < 4096; idx += stride) {
    int n = idx >> 7, k = idx & 127;
    w3t[idx] = (n < 30) ? (f16)gdw3[k * 30 + n] : (f16)0.0f;
  }
}

// ======================= Kernel B: decoder MLP =======================
extern "C" __global__ __launch_bounds__(256, 2)
void hwq_dec(const f16* __restrict__ wz, const f16* __restrict__ w1t,
             const f16* __restrict__ w2t, const f16* __restrict__ w3t,
             const float* __restrict__ gdb1, const float* __restrict__ gdb2,
             const float* __restrict__ gdb3, float* __restrict__ gout)
{
  __shared__ __align__(16) char smem[55296];
  f16* a1 = (f16*)smem;               // [64][280]
  f16* a2 = (f16*)(smem + 35840);     // [64][152]
  const int tid = threadIdx.x;
  const int lane = tid & 63;
  const int wv = tid >> 6;
  const int lr = lane & 15;
  const int lk = lane >> 4;
  const int s0 = blockIdx.x << 6;

  f32x4 acc1[4][4];
  #pragma unroll
  for (int nt = 0; nt < 4; ++nt) {
    float bb = gdb1[wv * 64 + nt * 16 + lr];
    f32x4 bv = {bb, bb, bb, bb};
    #pragma unroll
    for (int mt = 0; mt < 4; ++mt) acc1[mt][nt] = bv;
  }
  for (int kt = 0; kt < 17; ++kt) {
    f16x8 af[4];
    #pragma unroll
    for (int mt = 0; mt < 4; ++mt)
      af[mt] = *(const f16x8*)(wz + (size_t)(s0 + mt * 16 + lr) * 544 + kt * 32 + lk * 8);
    #pragma unroll
    for (int nt = 0; nt < 4; ++nt) {
      f16x8 bf = *(const f16x8*)(w1t + (size_t)(wv * 64 + nt * 16 + lr) * 544 + kt * 32 + lk * 8);
      #pragma unroll
      for (int mt = 0; mt < 4; ++mt)
        acc1[mt][nt] = MFMA16(af[mt], bf, acc1[mt][nt]);
    }
  }
  #pragma unroll
  for (int mt = 0; mt < 4; ++mt)
    #pragma unroll
    for (int nt = 0; nt < 4; ++nt) {
      int n = wv * 64 + nt * 16 + lr;
      #pragma unroll
      for (int r = 0; r < 4; ++r)
        a1[(mt * 16 + lk * 4 + r) * 280 + n] = (f16)fmaxf(acc1[mt][nt][r], 0.0f);
    }
  __syncthreads();

  f32x4 acc2[4][2];
  #pragma unroll
  for (int nt = 0; nt < 2; ++nt) {
    float bb = gdb2[wv * 32 + nt * 16 + lr];
    f32x4 bv = {bb, bb, bb, bb};
    #pragma unroll
    for (int mt = 0; mt < 4; ++mt) acc2[mt][nt] = bv;
  }
  for (int kt = 0; kt < 8; ++kt) {
    f16x8 af[4];
    #pragma unroll
    for (int mt = 0; mt < 4; ++mt)
      af[mt] = *(const f16x8*)(a1 + (mt * 16 + lr) * 280 + kt * 32 + lk * 8);
    #pragma unroll
    for (int nt = 0; nt < 2; ++nt) {
      f16x8 bf = *(const f16x8*)(w2t + (size_t)(wv * 32 + nt * 16 + lr) * 256 + kt * 32 + lk * 8);
      #pragma unroll
      for (int mt = 0; mt < 4; ++mt)
        acc2[mt][nt] = MFMA16(af[mt], bf, acc2[mt][nt]);
    }
  }
  __syncthreads();
  #pragma unroll
  for (int mt = 0; mt < 4; ++mt)
    #pragma unroll
    for (int nt = 0; nt < 2; ++nt) {
      int n = wv * 32 + nt * 16 + lr;
      #pragma unroll
      for (int r = 0; r < 4; ++r)
        a2[(mt * 16 + lk * 4 + r) * 152 + n] = (f16)fmaxf(acc2[mt][nt][r], 0.0f);
    }
  __syncthreads();

  if (wv < 2) {
    int n = wv * 16 + lr;
    float bb = (n < 30) ? gdb3[n] : 0.0f;
    f32x4 acc3[4];
    #pragma unroll
    for (int mt = 0; mt < 4; ++mt) { f32x4 bv = {bb, bb, bb, bb}; acc3[mt] = bv; }
    #pragma unroll
    for (int kt = 0; kt < 4; ++kt) {
      f16x8 bf = *(const f16x8*)(w3t + n * 128 + kt * 32 + lk * 8);
      #pragma unroll
      for (int mt = 0; mt < 4; ++mt) {
        f16x8 af = *(const f16x8*)(a2 + (mt * 16 + lr) * 152 + kt * 32 + lk * 8);
        acc3[mt] = MFMA16(af, bf, acc3[mt]);
      }
    }
    if (n < 30) {
      #pragma unroll
      for (int mt = 0; mt < 4; ++mt)
        #pragma unroll
        for (int r = 0; r < 4; ++r)
          gout[(size_t)(s0 + mt * 16 + lk * 4 + r) * 30 + n] = sigm(acc3[mt][r]);
    }
  }
}

// ======================= Fallback: monolithic kernel (R1) =======================
typedef _Float16 f16x4m __attribute__((ext_vector_type(4)));
#define OFF_B 46080
#define SMEM_BYTES (46080 + 17408)

extern "C" __global__ __launch_bounds__(256, 1)
void hwq_fused_mono(const float* __restrict__ gx, const float* __restrict__ ghour,
               const float* __restrict__ gcw, const float* __restrict__ gcb,
               const float* __restrict__ ghw1, const float* __restrict__ ghb1,
               const float* __restrict__ ghw2, const float* __restrict__ ghb2,
               const float* __restrict__ gdw1, const float* __restrict__ gdb1,
               const float* __restrict__ gdw2, const float* __restrict__ gdb2,
               const float* __restrict__ gdw3, const float* __restrict__ gdb3,
               float* __restrict__ gout)
{
  __shared__ __align__(16) char smem[SMEM_BYTES];
  const int tid = threadIdx.x;
  const int lane = tid & 63;
  const int wv = tid >> 6;
  const int mg = wv & 1;
  const int ng = wv >> 1;
  const int lr = lane & 15;
  const int lk = lane >> 4;
  const int bg = blockIdx.x << 4;

  f16x8 Ah[9][4];
  {
    f16* wst = (f16*)(smem);
    #pragma unroll
    for (int c = 0; c < 2; ++c) {
      __syncthreads();
      for (int i = tid; i < 18432; i += 256) {
        int oc = i / 288, rem = i - oc * 288;
        wst[i] = (f16)gcw[(c * 64 + oc) * 315 + 27 + rem];
      }
      __syncthreads();
      #pragma unroll
      for (int g = 0; g < 2; ++g) {
        int ocl = g * 32 + mg * 16 + lr;
        #pragma unroll
        for (int tap = 0; tap < 9; ++tap) {
          f16x8 f;
          #pragma unroll
          for (int j = 0; j < 8; ++j)
            f[j] = wst[ocl * 288 + (lk * 8 + j) * 9 + tap];
          Ah[tap][c * 2 + g] = f;
        }
      }
    }
  }
  f16x8 Ax[4];
  {
    f16* xw = (f16*)(smem + OFF_B);
    __syncthreads();
    for (int i = tid; i < 3456; i += 256) {
      int oc = i / 27, rem = i - oc * 27;
      xw[i] = (f16)gcw[oc * 315 + rem];
    }
    __syncthreads();
    #pragma unroll
    for (int mt = 0; mt < 4; ++mt) {
      int oc = mt * 32 + mg * 16 + lr;
      f16x8 f;
      #pragma unroll
      for (int j = 0; j < 8; ++j) {
        int k = lk * 8 + j;
        int tap = (k * 11) >> 5;
        int ic = k - 3 * tap;
        f16 v = (f16)0.0f;
        if (k < 27) v = xw[oc * 27 + ic * 9 + tap];
        f[j] = v;
      }
      Ax[mt] = f;
    }
    __syncthreads();
  }

  float bias[4][4];
  #pragma unroll
  for (int mt = 0; mt < 4; ++mt)
    #pragma unroll
    for (int r = 0; r < 4; ++r)
      bias[mt][r] = gcb[mt * 32 + mg * 16 + lk * 4 + r];

  {
    float* za = (float*)smem;
    for (int i = tid; i < 11520; i += 256) za[i] = 0.0f;
    float* zb = (float*)(smem + OFF_B);
    for (int i = tid; i < 1152; i += 256) zb[i] = 0.0f;
    __syncthreads();
    for (int i = tid; i < 768; i += 256) {
      int b = i / 48, rem = i - b * 48;
      int pos = rem & 15;
      int ic = rem >> 4;
      int pp = (pos >> 2) * 6 + (pos & 3) + 7;
      *(f16*)(smem + OFF_B + b * 288 + pp * 8 + ic * 2) =
          (f16)gx[(size_t)(bg + b) * 576 + rem];
    }
    __syncthreads();
  }

  int hbase[8], xbase[8], wbase[8];
  #pragma unroll
  for (int nt = 0; nt < 8; ++nt) {
    int n = ng * 128 + nt * 16 + lr;
    int b = n >> 4, pos = n & 15;
    int pp0 = (pos >> 2) * 6 + (pos & 3);
    hbase[nt] = b * 2880 + pp0 * 80 + lk * 16;
    xbase[nt] = OFF_B + b * 288 + pp0 * 8;
    wbase[nt] = b * 2880 + (pp0 + 7) * 80 + (mg * 16 + lk * 4) * 2;
  }
  int xoff[8], xval[8];
  #pragma unroll
  for (int j = 0; j < 8; ++j) {
    int k = lk * 8 + j;
    int tap = (k * 11) >> 5;
    int ic = k - 3 * tap;
    xoff[j] = ((tap / 3) * 6 + (tap % 3)) * 8 + ic * 2;
    xval[j] = (k < 27);
  }

  const int TOFF[9] = {0, 1, 2, 6, 7, 8, 12, 13, 14};

  f32x4 cst[8];
  #pragma unroll
  for (int nt = 0; nt < 8; ++nt) { f32x4 z = {0.f, 0.f, 0.f, 0.f}; cst[nt] = z; }

  for (int t = 0; t < 12; ++t) {
    f32x4 acc[4][8];
    #pragma unroll
    for (int mt = 0; mt < 4; ++mt) {
      f32x4 bi = {bias[mt][0], bias[mt][1], bias[mt][2], bias[mt][3]};
      #pragma unroll
      for (int nt = 0; nt < 8; ++nt) acc[mt][nt] = bi;
    }
    #pragma unroll
    for (int tap = 0; tap < 9; ++tap) {
      #pragma unroll
      for (int nt = 0; nt < 8; ++nt) {
        f16x8 bf = *(const f16x8*)(smem + hbase[nt] + TOFF[tap] * 80);
        #pragma unroll
        for (int mt = 0; mt < 4; ++mt)
          acc[mt][nt] = MFMA16(Ah[tap][mt], bf, acc[mt][nt]);
      }
    }
    #pragma unroll
    for (int nt = 0; nt < 8; ++nt) {
      f16x8 bf;
      #pragma unroll
      for (int j = 0; j < 8; ++j) {
        int a = xval[j] ? (xbase[nt] + xoff[j]) : OFF_B;
        bf[j] = *(const f16*)(smem + a);
      }
      #pragma unroll
      for (int mt = 0; mt < 4; ++mt)
        acc[mt][nt] = MFMA16(Ax[mt], bf, acc[mt][nt]);
    }
    __syncthreads();

    #pragma unroll
    for (int nt = 0; nt < 8; ++nt) {
      f16 hh[4];
      #pragma unroll
      for (int r = 0; r < 4; ++r) {
        float ig = sigm(acc[0][nt][r]);
        float fg = sigm(acc[1][nt][r]);
        float og = sigm(acc[2][nt][r]);
        float gg = tanh_(acc[3][nt][r]);
        float cn = fg * cst[nt][r] + ig * gg;
        cst[nt][r] = cn;
        hh[r] = (f16)(og * tanh_(cn));
      }
      if (t < 11) {
        f16x4m hv = {hh[0], hh[1], hh[2], hh[3]};
        *(f16x4m*)(smem + wbase[nt]) = hv;
      } else {
        int n = ng * 128 + nt * 16 + lr;
        int b = n >> 4, pos = n & 15;
        int ch0 = mg * 16 + lk * 4;
        #pragma unroll
        for (int r = 0; r < 4; ++r)
          *(f16*)(smem + OFF_B + b * 1088 + (ch0 + r) * 32 + pos * 2) = hh[r];
      }
    }
    if (t < 11) {
      for (int i = tid; i < 768; i += 256) {
        int b = i / 48, rem = i - b * 48;
        int pos = rem & 15;
        int ic = rem >> 4;
        int pp = (pos >> 2) * 6 + (pos & 3) + 7;
        *(f16*)(smem + OFF_B + b * 288 + pp * 8 + ic * 2) =
            (f16)gx[(size_t)(bg + b) * 576 + (t + 1) * 48 + rem];
      }
    } else {
      for (int i = tid; i < 512; i += 256) {
        int b = i >> 5, k2 = i & 31;
        float h0 = ghour[bg + b];
        float a = ghb2[k2];
        #pragma unroll
        for (int ii = 0; ii < 16; ++ii) {
          float u = fmaxf(h0 * ghw1[ii] + ghb1[ii], 0.0f);
          a += u * ghw2[ii * 32 + k2];
        }
        *(f16*)(smem + OFF_B + b * 1088 + (512 + k2) * 2) = (f16)a;
      }
    }
    __syncthreads();
  }

  f16* zz  = (f16*)(smem + OFF_B);
  f16* wch = (f16*)(smem);
  f16* a1  = (f16*)(smem + 16384);
  f16* a2  = (f16*)(smem + 24576);
  f16* w3s = (f16*)(smem + 28672);

  f32x4 acc1[4];
  #pragma unroll
  for (int i = 0; i < 4; ++i) { f32x4 z = {0.f, 0.f, 0.f, 0.f}; acc1[i] = z; }
  for (int kt = 0; kt < 17; ++kt) {
    __syncthreads();
    for (int i = tid; i < 8192; i += 256) {
      int k = i >> 8, n = i & 255;
      wch[i] = (f16)gdw1[(kt * 32 + k) * 256 + n];
    }
    __syncthreads();
    f16x8 af = *(const f16x8*)((char*)zz + lr * 1088 + (kt * 32 + lk * 8) * 2);
    #pragma unroll
    for (int nt = 0; nt < 4; ++nt) {
      int n = (wv * 4 + nt) * 16 + lr;
      f16x8 bf;
      #pragma unroll
      for (int j = 0; j < 8; ++j) bf[j] = wch[(lk * 8 + j) * 256 + n];
      acc1[nt] = MFMA16(af, bf, acc1[nt]);
    }
  }
  __syncthreads();
  #pragma unroll
  for (int nt = 0; nt < 4; ++nt) {
    int n = (wv * 4 + nt) * 16 + lr;
    float bb = gdb1[n];
    #pragma unroll
    for (int r = 0; r < 4; ++r)
      a1[(lk * 4 + r) * 256 + n] = (f16)fmaxf(acc1[nt][r] + bb, 0.0f);
  }

  f32x4 acc2[2];
  #pragma unroll
  for (int i = 0; i < 2; ++i) { f32x4 z = {0.f, 0.f, 0.f, 0.f}; acc2[i] = z; }
  for (int kt = 0; kt < 8; ++kt) {
    __syncthreads();
    for (int i = tid; i < 4096; i += 256) {
      int k = i >> 7, n = i & 127;
      wch[i] = (f16)gdw2[(kt * 32 + k) * 128 + n];
    }
    __syncthreads();
    f16x8 af = *(const f16x8*)((char*)a1 + lr * 512 + (kt * 32 + lk * 8) * 2);
    #pragma unroll
    for (int nt = 0; nt < 2; ++nt) {
      int n = (wv * 2 + nt) * 16 + lr;
      f16x8 bf;
      #pragma unroll
      for (int j = 0; j < 8; ++j) bf[j] = wch[(lk * 8 + j) * 128 + n];
      acc2[nt] = MFMA16(af, bf, acc2[nt]);
    }
  }
  __syncthreads();
  #pragma unroll
  for (int nt = 0; nt < 2; ++nt) {
    int n = (wv * 2 + nt) * 16 + lr;
    float bb = gdb2[n];
    #pragma unroll
    for (int r = 0; r < 4; ++r)
      a2[(lk * 4 + r) * 128 + n] = (f16)fmaxf(acc2[nt][r] + bb, 0.0f);
  }
  __syncthreads();

  for (int i = tid; i < 4096; i += 256) {
    int k = i >> 5, n = i & 31;
    w3s[i] = (n < 30) ? (f16)gdw3[k * 30 + n] : (f16)0.0f;
  }
  __syncthreads();
  if (wv < 2) {
    f32x4 acc3 = {0.f, 0.f, 0.f, 0.f};
    int n = wv * 16 + lr;
    #pragma unroll
    for (int kt = 0; kt < 4; ++kt) {
      f16x8 af = *(const f16x8*)((char*)a2 + lr * 256 + (kt * 32 + lk * 8) * 2);
      f16x8 bf;
      #pragma unroll
      for (int j = 0; j < 8; ++j) bf[j] = w3s[(kt * 32 + lk * 8 + j) * 32 + n];
      acc3 = MFMA16(af, bf, acc3);
    }
    if (n < 30) {
      float bb = gdb3[n];
      #pragma unroll
      for (int r = 0; r < 4; ++r) {
        float v = sigm(acc3[r] + bb);
        gout[(size_t)(bg + lk * 4 + r) * 30 + n] = v;
      }
    }
  }
}

extern "C" void kernel_launch(void* const* d_in, const int* in_sizes, int n_in,
                              void* d_out, int out_size, void* d_ws, size_t ws_size,
                              hipStream_t stream) {
  (void)in_sizes; (void)n_in; (void)out_size;
  const size_t W1OFF = 35651584;             // z: 32768*544*2
  const size_t W2OFF = W1OFF + 278528;       // w1t
  const size_t W3OFF = W2OFF + 65536;        // w2t
  const size_t NEED  = W3OFF + 8192;         // w3t
  if (ws_size >= NEED) {
    f16* wzp = (f16*)d_ws;
    f16* w1t = (f16*)((char*)d_ws + W1OFF);
    f16* w2t = (f16*)((char*)d_ws + W2OFF);
    f16* w3t = (f16*)((char*)d_ws + W3OFF);
    hwq_prep<<<256, 256, 0, stream>>>((const float*)d_in[8], (const float*)d_in[10],
                                      (const float*)d_in[12], w1t, w2t, w3t);
    hwq_rec<<<GRID_REC, 256, 0, stream>>>(
        (const float*)d_in[0], (const float*)d_in[1], (const float*)d_in[2],
        (const float*)d_in[3], (const float*)d_in[4], (const float*)d_in[5],
        (const float*)d_in[6], (const float*)d_in[7], wzp);
    hwq_dec<<<512, 256, 0, stream>>>(wzp, w1t, w2t, w3t,
                                     (const float*)d_in[9], (const float*)d_in[11],
                                     (const float*)d_in[13], (float*)d_out);
  } else {
    hwq_fused_mono<<<2048, 256, 0, stream>>>(
        (const float*)d_in[0],  (const float*)d_in[1],  (const float*)d_in[2],
        (const float*)d_in[3],  (const float*)d_in[4],  (const float*)d_in[5],
        (const float*)d_in[6],  (const float*)d_in[7],  (const float*)d_in[8],
        (const float*)d_in[9],  (const float*)d_in[10], (const float*)d_in[11],
        (const float*)d_in[12], (const float*)d_in[13], (float*)d_out);
  }
}

// Round 7
// 716.409 us; speedup vs baseline: 1.6105x; 1.1280x over previous
//
#include <hip/hip_runtime.h>

typedef _Float16 f16;
typedef _Float16 f16x4 __attribute__((ext_vector_type(4)));
typedef _Float16 f16x8 __attribute__((ext_vector_type(8)));
typedef float f32x2 __attribute__((ext_vector_type(2)));
typedef float f32x4 __attribute__((ext_vector_type(4)));

#define MFMA16(a, b, c) __builtin_amdgcn_mfma_f32_16x16x32_f16((a), (b), (c), 0, 0, 0)

__device__ __forceinline__ float rcp_(float x) { return __builtin_amdgcn_rcpf(x); }
__device__ __forceinline__ float sigm(float v) { return rcp_(1.0f + __expf(-v)); }
__device__ __forceinline__ float tanh_(float v) { return 1.0f - 2.0f * rcp_(__expf(2.0f * v) + 1.0f); }

// ============ Kernel A: persistent ConvLSTM recurrence (all-register A) ========
// Grid 512 (2 blocks/CU), each block sweeps 16 groups of 4 samples (prologue
// amortized over 192 t-steps). 256 threads = 4 waves = mg(0..1) x ng(0..1).
// Wave tile M=64 x N=32: m = ch*4+gate (gate-interleaved), 4 m-tiles; n-tiles =
// samples ng*2+nt, pos = lr. ALL 9 tap A-frags in registers (144 VGPR) -> hot
// loop LDS = B-frags (18 b128/wave) + x (6 b64) + h' writes (8 b16) only.
// B duplication only x2 (the two mg waves), vs x4 in R6.
// launch_bounds(256,2): 256 unified regs/wave -> no spill (R6 spilled at 128).
//
// LDS: hpad [4 b][36 cell][36 sl f16] 0..10368 (cell 72 B, sample 2592 B)
//      xpad [4 b][36 cell][4 sl f16]  10368..11520 (sl: 3 ic + bias flag)
//      WS prologue scratch            11520..29952
#define XP 10368
#define WSO 11520
#define SMEMA 29952
#define NGRP 8192
#define GRID_REC 512

extern "C" __global__ __launch_bounds__(256, 2)
void hwq_rec(const float* __restrict__ gx, const float* __restrict__ ghour,
             const float* __restrict__ gcw, const float* __restrict__ gcb,
             const float* __restrict__ ghw1, const float* __restrict__ ghb1,
             const float* __restrict__ ghw2, const float* __restrict__ ghb2,
             f16* __restrict__ wz)
{
  __shared__ __align__(16) char smem[SMEMA];
  const int tid = threadIdx.x;
  const int lane = tid & 63;
  const int wv = tid >> 6;
  const int mg = wv & 1;                // M-half: m in [mg*64, mg*64+64)
  const int ng = wv >> 1;               // N-half: samples ng*2, ng*2+1
  const int lr = lane & 15;
  const int lk = lane >> 4;
  const int TOFF[9] = {0, 1, 2, 6, 7, 8, 12, 13, 14};
  const int pp0 = (lr >> 2) * 6 + (lr & 3);

  // ---- prologue 1: zero hpad+xpad; stage Ax1 table [128 m][32 k] into WS ----
  {
    float* za = (float*)smem;
    for (int i = tid; i < 2880; i += 256) za[i] = 0.0f;
    f16* axs = (f16*)(smem + WSO);
    for (int i = tid; i < 4096; i += 256) {
      int m = i >> 5, k = i & 31;
      int tau = k >> 2, sl = k & 3;
      int oc = ((m & 3) << 5) + (m >> 2);
      f16 v = (f16)0.0f;
      if (sl < 3) v = (f16)gcw[oc * 315 + sl * 9 + tau];
      else if (tau == 4) v = (f16)gcb[oc];
      axs[i] = v;
    }
    __syncthreads();
  }
  // ---- prologue 2: xpad bias flags; gather Ax1; Ax2 (tap 8) direct ----
  f16x8 Ax1[4], Ax2[4];
  {
    if (tid < 64) {
      int b = tid >> 4, p = tid & 15;
      int cell = ((p >> 2) + 1) * 6 + (p & 3) + 1;
      *(f16*)(smem + XP + b * 288 + cell * 8 + 6) = (f16)1.0f;
    }
    #pragma unroll
    for (int mt = 0; mt < 4; ++mt) {
      Ax1[mt] = *(const f16x8*)(smem + WSO + (mg * 64 + mt * 16 + lr) * 64 + lk * 16);
      int m = mg * 64 + mt * 16 + lr;
      int oc = ((m & 3) << 5) + (m >> 2);
      f16x8 f = {(f16)0, (f16)0, (f16)0, (f16)0, (f16)0, (f16)0, (f16)0, (f16)0};
      if (lk == 0) {
        f[0] = (f16)gcw[oc * 315 + 8];
        f[1] = (f16)gcw[oc * 315 + 17];
        f[2] = (f16)gcw[oc * 315 + 26];
      }
      Ax2[mt] = f;
    }
    __syncthreads();
  }
  // ---- prologue 3: ALL 9 tap A-frags via 4 staged chunks of 32 m-rows ----
  f16x8 Ah[9][4];
  {
    f16* wst = (f16*)(smem + WSO);   // [32 row][288 = ch*9+tap]
    #pragma unroll
    for (int c = 0; c < 4; ++c) {
      for (int i = tid; i < 9216; i += 256) {
        int mrow = i / 288, rem = i - mrow * 288;
        int m = c * 32 + mrow;
        int oc = ((m & 3) << 5) + (m >> 2);
        wst[i] = (f16)gcw[oc * 315 + 27 + rem];
      }
      __syncthreads();
      if (mg == (c >> 1)) {
        #pragma unroll
        for (int mtl = 0; mtl < 2; ++mtl) {
          int mt = (c & 1) * 2 + mtl;
          #pragma unroll
          for (int tap = 0; tap < 9; ++tap) {
            f16x8 f;
            #pragma unroll
            for (int j = 0; j < 8; ++j)
              f[j] = wst[(mtl * 16 + lr) * 288 + (lk * 8 + j) * 9 + tap];
            Ah[tap][mt] = f;
          }
        }
      }
      __syncthreads();
    }
  }

  // ---- hot-loop bases (group-invariant) ----
  const int hb  = (ng * 2) * 2592 + pp0 * 72 + lk * 16;        // + nt*2592 + TOFF*72
  const int xpb = XP + (ng * 2) * 288 + pp0 * 8;               // + nt*288
  const int wb  = (ng * 2) * 2592 + (pp0 + 7) * 72 + (mg * 16 + lk) * 2;  // + nt*2592 + mt*8
  const int xo0 = TOFF[2 * lk] * 8;
  const int xo1 = TOFF[2 * lk + 1] * 8;
  const bool stg = tid < 192;
  const int sb = tid / 48, srem = tid - sb * 48;
  const int sp = srem & 15, sic = srem >> 4;
  const int xdst = XP + sb * 288 + (((sp >> 2) + 1) * 6 + (sp & 3) + 1) * 8 + sic * 2;
  const int zb_ = tid >> 6, zc16 = (tid >> 2) & 15, zpart = tid & 3;
  const int zaddr = zb_ * 2592 + ((zc16 >> 2) * 6 + (zc16 & 3) + 7) * 72 + zpart * 16;

  for (int grp = blockIdx.x; grp < NGRP; grp += GRID_REC) {
    const int bg = grp << 2;
    const float* gxb = gx + (size_t)bg * 576;
    const float* xsrc = gxb + (size_t)sb * 576 + srem;

    // group re-init: zero hpad interior (h0 = 0), stage xpad(t=0)
    {
      f32x2 z2 = {0.f, 0.f};
      *(f32x2*)(smem + zaddr) = z2;
      *(f32x2*)(smem + zaddr + 8) = z2;
    }
    if (stg) *(f16*)(smem + xdst) = (f16)xsrc[0];
    float cst[4][2];
    #pragma unroll
    for (int mt = 0; mt < 4; ++mt) { cst[mt][0] = 0.0f; cst[mt][1] = 0.0f; }
    __syncthreads();

    for (int t = 0; t < 12; ++t) {
      float xv = 0.0f;
      if (t < 11 && stg) xv = xsrc[(t + 1) * 48];   // prefetch next x early

      f32x4 acc[4][2];
      #pragma unroll
      for (int mt = 0; mt < 4; ++mt)
        #pragma unroll
        for (int nt = 0; nt < 2; ++nt) { f32x4 z = {0.f, 0.f, 0.f, 0.f}; acc[mt][nt] = z; }

      // 9 tap-GEMMs, all A in registers
      #pragma unroll
      for (int tap = 0; tap < 9; ++tap) {
        const int to = TOFF[tap] * 72;
        #pragma unroll
        for (int nt = 0; nt < 2; ++nt) {
          f16x8 bf = *(const f16x8*)(smem + hb + nt * 2592 + to);
          #pragma unroll
          for (int mt = 0; mt < 4; ++mt)
            acc[mt][nt] = MFMA16(Ah[tap][mt], bf, acc[mt][nt]);
        }
      }
      // x + bias (2 MFMAs per (mt,nt); B from 3 ds_read_b64 per nt)
      #pragma unroll
      for (int nt = 0; nt < 2; ++nt) {
        const int base = xpb + nt * 288;
        f16x4 lo = *(const f16x4*)(smem + base + xo0);
        f16x4 hi = *(const f16x4*)(smem + base + xo1);
        f16x8 bf1 = __builtin_shufflevector(lo, hi, 0, 1, 2, 3, 4, 5, 6, 7);
        f16x4 l8 = *(const f16x4*)(smem + base + 112);
        f16x8 bf2 = __builtin_shufflevector(l8, l8, 0, 1, 2, 3, 0, 1, 2, 3);
        #pragma unroll
        for (int mt = 0; mt < 4; ++mt) {
          acc[mt][nt] = MFMA16(Ax1[mt], bf1, acc[mt][nt]);
          acc[mt][nt] = MFMA16(Ax2[mt], bf2, acc[mt][nt]);
        }
      }
      __syncthreads();   // all hpad/xpad reads done

      // cell update in-register: acc[mt][nt] = (i,f,o,g) of channel mg*16+mt*4+lk
      #pragma unroll
      for (int mt = 0; mt < 4; ++mt) {
        #pragma unroll
        for (int nt = 0; nt < 2; ++nt) {
          float ig = sigm(acc[mt][nt][0]);
          float fg = sigm(acc[mt][nt][1]);
          float og = sigm(acc[mt][nt][2]);
          float gg = tanh_(acc[mt][nt][3]);
          float cn = fg * cst[mt][nt] + ig * gg;
          cst[mt][nt] = cn;
          f16 h = (f16)(og * tanh_(cn));
          if (t < 11) {
            *(f16*)(smem + wb + nt * 2592 + mt * 8) = h;
          } else {
            int ch = mg * 16 + mt * 4 + lk;
            wz[(size_t)(bg + ng * 2 + nt) * 544 + ch * 16 + lr] = h;
          }
        }
      }
      if (t < 11) {
        if (stg) *(f16*)(smem + xdst) = (f16)xv;
      } else if (tid < 128) {
        int b = tid >> 5, k2 = tid & 31;
        float h0 = ghour[bg + b];
        float a = ghb2[k2];
        #pragma unroll
        for (int ii = 0; ii < 16; ++ii) {
          float u = fmaxf(h0 * ghw1[ii] + ghb1[ii], 0.0f);
          a += u * ghw2[ii * 32 + k2];
        }
        wz[(size_t)(bg + b) * 544 + 512 + k2] = (f16)a;
      }
      __syncthreads();
    }
  }
}

// ======================= prep: weight transpose fp32->f16 =======================
extern "C" __global__ void hwq_prep(const float* __restrict__ gdw1,
                                    const float* __restrict__ gdw2,
                                    const float* __restrict__ gdw3,
                                    f16* __restrict__ w1t, f16* __restrict__ w2t,
                                    f16* __restrict__ w3t)
{
  int i0 = blockIdx.x * 256 + threadIdx.x;
  int stride = gridDim.x * 256;
  for (int idx = i0; idx < 139264; idx += stride) {
    int n = idx / 544, k = idx - n * 544;
    w1t[idx] = (f16)gdw1[k * 256 + n];
  }
  for (int idx = i0; idx < 32768; idx += stride) {
    int n = idx >> 8, k = idx & 255;
    w2t[idx] = (f16)gdw2[k * 128 + n];
  }
  for (int idx = i0; idx < 4096; idx += stride) {
    int n = idx >> 7, k = idx & 127;
    w3t[idx] = (n < 30) ? (f16)gdw3[k * 30 + n] : (f16)0.0f;
  }
}

// ======================= Kernel B: decoder MLP =======================
extern "C" __global__ __launch_bounds__(256, 2)
void hwq_dec(const f16* __restrict__ wz, const f16* __restrict__ w1t,
             const f16* __restrict__ w2t, const f16* __restrict__ w3t,
             const float* __restrict__ gdb1, const float* __restrict__ gdb2,
             const float* __restrict__ gdb3, float* __restrict__ gout)
{
  __shared__ __align__(16) char smem[55296];
  f16* a1 = (f16*)smem;               // [64][280]
  f16* a2 = (f16*)(smem + 35840);     // [64][152]
  const int tid = threadIdx.x;
  const int lane = tid & 63;
  const int wv = tid >> 6;
  const int lr = lane & 15;
  const int lk = lane >> 4;
  const int s0 = blockIdx.x << 6;

  f32x4 acc1[4][4];
  #pragma unroll
  for (int nt = 0; nt < 4; ++nt) {
    float bb = gdb1[wv * 64 + nt * 16 + lr];
    f32x4 bv = {bb, bb, bb, bb};
    #pragma unroll
    for (int mt = 0; mt < 4; ++mt) acc1[mt][nt] = bv;
  }
  for (int kt = 0; kt < 17; ++kt) {
    f16x8 af[4];
    #pragma unroll
    for (int mt = 0; mt < 4; ++mt)
      af[mt] = *(const f16x8*)(wz + (size_t)(s0 + mt * 16 + lr) * 544 + kt * 32 + lk * 8);
    #pragma unroll
    for (int nt = 0; nt < 4; ++nt) {
      f16x8 bf = *(const f16x8*)(w1t + (size_t)(wv * 64 + nt * 16 + lr) * 544 + kt * 32 + lk * 8);
      #pragma unroll
      for (int mt = 0; mt < 4; ++mt)
        acc1[mt][nt] = MFMA16(af[mt], bf, acc1[mt][nt]);
    }
  }
  #pragma unroll
  for (int mt = 0; mt < 4; ++mt)
    #pragma unroll
    for (int nt = 0; nt < 4; ++nt) {
      int n = wv * 64 + nt * 16 + lr;
      #pragma unroll
      for (int r = 0; r < 4; ++r)
        a1[(mt * 16 + lk * 4 + r) * 280 + n] = (f16)fmaxf(acc1[mt][nt][r], 0.0f);
    }
  __syncthreads();

  f32x4 acc2[4][2];
  #pragma unroll
  for (int nt = 0; nt < 2; ++nt) {
    float bb = gdb2[wv * 32 + nt * 16 + lr];
    f32x4 bv = {bb, bb, bb, bb};
    #pragma unroll
    for (int mt = 0; mt < 4; ++mt) acc2[mt][nt] = bv;
  }
  for (int kt = 0; kt < 8; ++kt) {
    f16x8 af[4];
    #pragma unroll
    for (int mt = 0; mt < 4; ++mt)
      af[mt] = *(const f16x8*)(a1 + (mt * 16 + lr) * 280 + kt * 32 + lk * 8);
    #pragma unroll
    for (int nt = 0; nt < 2; ++nt) {
      f16x8 bf = *(const f16x8*)(w2t + (size_t)(wv * 32 + nt * 16 + lr) * 256 + kt * 32 + lk * 8);
      #pragma unroll
      for (int mt = 0; mt < 4; ++mt)
        acc2[mt][nt] = MFMA16(af[mt], bf, acc2[mt][nt]);
    }
  }
  __syncthreads();
  #pragma unroll
  for (int mt = 0; mt < 4; ++mt)
    #pragma unroll
    for (int nt = 0; nt < 2; ++nt) {
      int n = wv * 32 + nt * 16 + lr;
      #pragma unroll
      for (int r = 0; r < 4; ++r)
        a2[(mt * 16 + lk * 4 + r) * 152 + n] = (f16)fmaxf(acc2[mt][nt][r], 0.0f);
    }
  __syncthreads();

  if (wv < 2) {
    int n = wv * 16 + lr;
    float bb = (n < 30) ? gdb3[n] : 0.0f;
    f32x4 acc3[4];
    #pragma unroll
    for (int mt = 0; mt < 4; ++mt) { f32x4 bv = {bb, bb, bb, bb}; acc3[mt] = bv; }
    #pragma unroll
    for (int kt = 0; kt < 4; ++kt) {
      f16x8 bf = *(const f16x8*)(w3t + n * 128 + kt * 32 + lk * 8);
      #pragma unroll
      for (int mt = 0; mt < 4; ++mt) {
        f16x8 af = *(const f16x8*)(a2 + (mt * 16 + lr) * 152 + kt * 32 + lk * 8);
        acc3[mt] = MFMA16(af, bf, acc3[mt]);
      }
    }
    if (n < 30) {
      #pragma unroll
      for (int mt = 0; mt < 4; ++mt)
        #pragma unroll
        for (int r = 0; r < 4; ++r)
          gout[(size_t)(s0 + mt * 16 + lk * 4 + r) * 30 + n] = sigm(acc3[mt][r]);
    }
  }
}

// ======================= Fallback: monolithic kernel (R1) =======================
typedef _Float16 f16x4m __attribute__((ext_vector_type(4)));
#define OFF_B 46080
#define SMEM_BYTES (46080 + 17408)

extern "C" __global__ __launch_bounds__(256, 1)
void hwq_fused_mono(const float* __restrict__ gx, const float* __restrict__ ghour,
               const float* __restrict__ gcw, const float* __restrict__ gcb,
               const float* __restrict__ ghw1, const float* __restrict__ ghb1,
               const float* __restrict__ ghw2, const float* __restrict__ ghb2,
               const float* __restrict__ gdw1, const float* __restrict__ gdb1,
               const float* __restrict__ gdw2, const float* __restrict__ gdb2,
               const float* __restrict__ gdw3, const float* __restrict__ gdb3,
               float* __restrict__ gout)
{
  __shared__ __align__(16) char smem[SMEM_BYTES];
  const int tid = threadIdx.x;
  const int lane = tid & 63;
  const int wv = tid >> 6;
  const int mg = wv & 1;
  const int ng = wv >> 1;
  const int lr = lane & 15;
  const int lk = lane >> 4;
  const int bg = blockIdx.x << 4;

  f16x8 Ah[9][4];
  {
    f16* wst = (f16*)(smem);
    #pragma unroll
    for (int c = 0; c < 2; ++c) {
      __syncthreads();
      for (int i = tid; i < 18432; i += 256) {
        int oc = i / 288, rem = i - oc * 288;
        wst[i] = (f16)gcw[(c * 64 + oc) * 315 + 27 + rem];
      }
      __syncthreads();
      #pragma unroll
      for (int g = 0; g < 2; ++g) {
        int ocl = g * 32 + mg * 16 + lr;
        #pragma unroll
        for (int tap = 0; tap < 9; ++tap) {
          f16x8 f;
          #pragma unroll
          for (int j = 0; j < 8; ++j)
            f[j] = wst[ocl * 288 + (lk * 8 + j) * 9 + tap];
          Ah[tap][c * 2 + g] = f;
        }
      }
    }
  }
  f16x8 Ax[4];
  {
    f16* xw = (f16*)(smem + OFF_B);
    __syncthreads();
    for (int i = tid; i < 3456; i += 256) {
      int oc = i / 27, rem = i - oc * 27;
      xw[i] = (f16)gcw[oc * 315 + rem];
    }
    __syncthreads();
    #pragma unroll
    for (int mt = 0; mt < 4; ++mt) {
      int oc = mt * 32 + mg * 16 + lr;
      f16x8 f;
      #pragma unroll
      for (int j = 0; j < 8; ++j) {
        int k = lk * 8 + j;
        int tap = (k * 11) >> 5;
        int ic = k - 3 * tap;
        f16 v = (f16)0.0f;
        if (k < 27) v = xw[oc * 27 + ic * 9 + tap];
        f[j] = v;
      }
      Ax[mt] = f;
    }
    __syncthreads();
  }

  float bias[4][4];
  #pragma unroll
  for (int mt = 0; mt < 4; ++mt)
    #pragma unroll
    for (int r = 0; r < 4; ++r)
      bias[mt][r] = gcb[mt * 32 + mg * 16 + lk * 4 + r];

  {
    float* za = (float*)smem;
    for (int i = tid; i < 11520; i += 256) za[i] = 0.0f;
    float* zb = (float*)(smem + OFF_B);
    for (int i = tid; i < 1152; i += 256) zb[i] = 0.0f;
    __syncthreads();
    for (int i = tid; i < 768; i += 256) {
      int b = i / 48, rem = i - b * 48;
      int pos = rem & 15;
      int ic = rem >> 4;
      int pp = (pos >> 2) * 6 + (pos & 3) + 7;
      *(f16*)(smem + OFF_B + b * 288 + pp * 8 + ic * 2) =
          (f16)gx[(size_t)(bg + b) * 576 + rem];
    }
    __syncthreads();
  }

  int hbase[8], xbase[8], wbase[8];
  #pragma unroll
  for (int nt = 0; nt < 8; ++nt) {
    int n = ng * 128 + nt * 16 + lr;
    int b = n >> 4, pos = n & 15;
    int pp0 = (pos >> 2) * 6 + (pos & 3);
    hbase[nt] = b * 2880 + pp0 * 80 + lk * 16;
    xbase[nt] = OFF_B + b * 288 + pp0 * 8;
    wbase[nt] = b * 2880 + (pp0 + 7) * 80 + (mg * 16 + lk * 4) * 2;
  }
  int xoff[8], xval[8];
  #pragma unroll
  for (int j = 0; j < 8; ++j) {
    int k = lk * 8 + j;
    int tap = (k * 11) >> 5;
    int ic = k - 3 * tap;
    xoff[j] = ((tap / 3) * 6 + (tap % 3)) * 8 + ic * 2;
    xval[j] = (k < 27);
  }

  const int TOFF[9] = {0, 1, 2, 6, 7, 8, 12, 13, 14};

  f32x4 cst[8];
  #pragma unroll
  for (int nt = 0; nt < 8; ++nt) { f32x4 z = {0.f, 0.f, 0.f, 0.f}; cst[nt] = z; }

  for (int t = 0; t < 12; ++t) {
    f32x4 acc[4][8];
    #pragma unroll
    for (int mt = 0; mt < 4; ++mt) {
      f32x4 bi = {bias[mt][0], bias[mt][1], bias[mt][2], bias[mt][3]};
      #pragma unroll
      for (int nt = 0; nt < 8; ++nt) acc[mt][nt] = bi;
    }
    #pragma unroll
    for (int tap = 0; tap < 9; ++tap) {
      #pragma unroll
      for (int nt = 0; nt < 8; ++nt) {
        f16x8 bf = *(const f16x8*)(smem + hbase[nt] + TOFF[tap] * 80);
        #pragma unroll
        for (int mt = 0; mt < 4; ++mt)
          acc[mt][nt] = MFMA16(Ah[tap][mt], bf, acc[mt][nt]);
      }
    }
    #pragma unroll
    for (int nt = 0; nt < 8; ++nt) {
      f16x8 bf;
      #pragma unroll
      for (int j = 0; j < 8; ++j) {
        int a = xval[j] ? (xbase[nt] + xoff[j]) : OFF_B;
        bf[j] = *(const f16*)(smem + a);
      }
      #pragma unroll
      for (int mt = 0; mt < 4; ++mt)
        acc[mt][nt] = MFMA16(Ax[mt], bf, acc[mt][nt]);
    }
    __syncthreads();

    #pragma unroll
    for (int nt = 0; nt < 8; ++nt) {
      f16 hh[4];
      #pragma unroll
      for (int r = 0; r < 4; ++r) {
        float ig = sigm(acc[0][nt][r]);
        float fg = sigm(acc[1][nt][r]);
        float og = sigm(acc[2][nt][r]);
        float gg = tanh_(acc[3][nt][r]);
        float cn = fg * cst[nt][r] + ig * gg;
        cst[nt][r] = cn;
        hh[r] = (f16)(og * tanh_(cn));
      }
      if (t < 11) {
        f16x4m hv = {hh[0], hh[1], hh[2], hh[3]};
        *(f16x4m*)(smem + wbase[nt]) = hv;
      } else {
        int n = ng * 128 + nt * 16 + lr;
        int b = n >> 4, pos = n & 15;
        int ch0 = mg * 16 + lk * 4;
        #pragma unroll
        for (int r = 0; r < 4; ++r)
          *(f16*)(smem + OFF_B + b * 1088 + (ch0 + r) * 32 + pos * 2) = hh[r];
      }
    }
    if (t < 11) {
      for (int i = tid; i < 768; i += 256) {
        int b = i / 48, rem = i - b * 48;
        int pos = rem & 15;
        int ic = rem >> 4;
        int pp = (pos >> 2) * 6 + (pos & 3) + 7;
        *(f16*)(smem + OFF_B + b * 288 + pp * 8 + ic * 2) =
            (f16)gx[(size_t)(bg + b) * 576 + (t + 1) * 48 + rem];
      }
    } else {
      for (int i = tid; i < 512; i += 256) {
        int b = i >> 5, k2 = i & 31;
        float h0 = ghour[bg + b];
        float a = ghb2[k2];
        #pragma unroll
        for (int ii = 0; ii < 16; ++ii) {
          float u = fmaxf(h0 * ghw1[ii] + ghb1[ii], 0.0f);
          a += u * ghw2[ii * 32 + k2];
        }
        *(f16*)(smem + OFF_B + b * 1088 + (512 + k2) * 2) = (f16)a;
      }
    }
    __syncthreads();
  }

  f16* zz  = (f16*)(smem + OFF_B);
  f16* wch = (f16*)(smem);
  f16* a1  = (f16*)(smem + 16384);
  f16* a2  = (f16*)(smem + 24576);
  f16* w3s = (f16*)(smem + 28672);

  f32x4 acc1[4];
  #pragma unroll
  for (int i = 0; i < 4; ++i) { f32x4 z = {0.f, 0.f, 0.f, 0.f}; acc1[i] = z; }
  for (int kt = 0; kt < 17; ++kt) {
    __syncthreads();
    for (int i = tid; i < 8192; i += 256) {
      int k = i >> 8, n = i & 255;
      wch[i] = (f16)gdw1[(kt * 32 + k) * 256 + n];
    }
    __syncthreads();
    f16x8 af = *(const f16x8*)((char*)zz + lr * 1088 + (kt * 32 + lk * 8) * 2);
    #pragma unroll
    for (int nt = 0; nt < 4; ++nt) {
      int n = (wv * 4 + nt) * 16 + lr;
      f16x8 bf;
      #pragma unroll
      for (int j = 0; j < 8; ++j) bf[j] = wch[(lk * 8 + j) * 256 + n];
      acc1[nt] = MFMA16(af, bf, acc1[nt]);
    }
  }
  __syncthreads();
  #pragma unroll
  for (int nt = 0; nt < 4; ++nt) {
    int n = (wv * 4 + nt) * 16 + lr;
    float bb = gdb1[n];
    #pragma unroll
    for (int r = 0; r < 4; ++r)
      a1[(lk * 4 + r) * 256 + n] = (f16)fmaxf(acc1[nt][r] + bb, 0.0f);
  }

  f32x4 acc2[2];
  #pragma unroll
  for (int i = 0; i < 2; ++i) { f32x4 z = {0.f, 0.f, 0.f, 0.f}; acc2[i] = z; }
  for (int kt = 0; kt < 8; ++kt) {
    __syncthreads();
    for (int i = tid; i < 4096; i += 256) {
      int k = i >> 7, n = i & 127;
      wch[i] = (f16)gdw2[(kt * 32 + k) * 128 + n];
    }
    __syncthreads();
    f16x8 af = *(const f16x8*)((char*)a1 + lr * 512 + (kt * 32 + lk * 8) * 2);
    #pragma unroll
    for (int nt = 0; nt < 2; ++nt) {
      int n = (wv * 2 + nt) * 16 + lr;
      f16x8 bf;
      #pragma unroll
      for (int j = 0; j < 8; ++j) bf[j] = wch[(lk * 8 + j) * 128 + n];
      acc2[nt] = MFMA16(af, bf, acc2[nt]);
    }
  }
  __syncthreads();
  #pragma unroll
  for (int nt = 0; nt < 2; ++nt) {
    int n = (wv * 2 + nt) * 16 + lr;
    float bb = gdb2[n];
    #pragma unroll
    for (int r = 0; r < 4; ++r)
      a2[(lk * 4 + r) * 128 + n] = (f16)fmaxf(acc2[nt][r] + bb, 0.0f);
  }
  __syncthreads();

  for (int i = tid; i < 4096; i += 256) {
    int k = i >> 5, n = i & 31;
    w3s[i] = (n < 30) ? (f16)gdw3[k * 30 + n] : (f16)0.0f;
  }
  __syncthreads();
  if (wv < 2) {
    f32x4 acc3 = {0.f, 0.f, 0.f, 0.f};
    int n = wv * 16 + lr;
    #pragma unroll
    for (int kt = 0; kt < 4; ++kt) {
      f16x8 af = *(const f16x8*)((char*)a2 + lr * 256 + (kt * 32 + lk * 8) * 2);
      f16x8 bf;
      #pragma unroll
      for (int j = 0; j < 8; ++j) bf[j] = w3s[(kt * 32 + lk * 8 + j) * 32 + n];
      acc3 = MFMA16(af, bf, acc3);
    }
    if (n < 30) {
      float bb = gdb3[n];
      #pragma unroll
      for (int r = 0; r < 4; ++r) {
        float v = sigm(acc3[r] + bb);
        gout[(size_t)(bg + lk * 4 + r) * 30 + n] = v;
      }
    }
  }
}

extern "C" void kernel_launch(void* const* d_in, const int* in_sizes, int n_in,
                              void* d_out, int out_size, void* d_ws, size_t ws_size,
                              hipStream_t stream) {
  (void)in_sizes; (void)n_in; (void)out_size;
  const size_t W1OFF = 35651584;             // z: 32768*544*2
  const size_t W2OFF = W1OFF + 278528;       // w1t
  const size_t W3OFF = W2OFF + 65536;        // w2t
  const size_t NEED  = W3OFF + 8192;         // w3t
  if (ws_size >= NEED) {
    f16* wzp = (f16*)d_ws;
    f16* w1t = (f16*)((char*)d_ws + W1OFF);
    f16* w2t = (f16*)((char*)d_ws + W2OFF);
    f16* w3t = (f16*)((char*)d_ws + W3OFF);
    hwq_prep<<<256, 256, 0, stream>>>((const float*)d_in[8], (const float*)d_in[10],
                                      (const float*)d_in[12], w1t, w2t, w3t);
    hwq_rec<<<GRID_REC, 256, 0, stream>>>(
        (const float*)d_in[0], (const float*)d_in[1], (const float*)d_in[2],
        (const float*)d_in[3], (const float*)d_in[4], (const float*)d_in[5],
        (const float*)d_in[6], (const float*)d_in[7], wzp);
    hwq_dec<<<512, 256, 0, stream>>>(wzp, w1t, w2t, w3t,
                                     (const float*)d_in[9], (const float*)d_in[11],
                                     (const float*)d_in[13], (float*)d_out);
  } else {
    hwq_fused_mono<<<2048, 256, 0, stream>>>(
        (const float*)d_in[0],  (const float*)d_in[1],  (const float*)d_in[2],
        (const float*)d_in[3],  (const float*)d_in[4],  (const float*)d_in[5],
        (const float*)d_in[6],  (const float*)d_in[7],  (const float*)d_in[8],
        (const float*)d_in[9],  (const float*)d_in[10], (const float*)d_in[11],
        (const float*)d_in[12], (const float*)d_in[13], (float*)d_out);
  }
}